// Round 1
// baseline (1840.948 us; speedup 1.0000x reference)
//
#include <hip/hip_runtime.h>
#include <stdint.h>

// IDUCell on MI355X (gfx950).
// Key algebraic facts exploited:
//   x0e  == xtes[:, S-1, :]   (x0 = x[:, -1])
//   p0e  == ptes[:, S-1, :]
//   zt   is h-independent: zt = sigmoid(xtes@Wxtz + bxtz + x0z)  -> precomputed
// Pipeline:
//   1. cast x -> bf16; init h_bf from h0
//   2. transpose-cast all GEMM weights to B^T (N x K) bf16 layout
//   3. GEMM1: xtes = relu(x@Wxe+b)        (writes f32 output + bf16 copy)
//   4. GEMM (small): x0rz = x0e@[Wx0r|Wx0z]+b
//   5. GEMM2 fused: [zt | xth1 | ptes] from xtes  (N = 1024+1024+31pad32)
//   6. persistent recurrence kernel: 64 blocks, weights strip in LDS,
//      per-step device barrier, h carried fp32 in regs, bf16 in global for MFMA
//   7. broadcast x0es / p0es slices

using bf16 = __bf16;
typedef __attribute__((ext_vector_type(8))) __bf16 bf16x8;
typedef __attribute__((ext_vector_type(4))) float f32x4;

#define B_DIM 64
#define S_DIM 64
#define F_DIM 4096
#define H_DIM 1024
#define C_DIM 31

// ---------------- elementwise ----------------

__global__ void cast_x_kernel(const float* __restrict__ in, bf16* __restrict__ out) {
  int i = blockIdx.x * 256 + threadIdx.x;   // 8 elems per thread
  const float4* p = (const float4*)in + (size_t)i * 2;
  float4 a = p[0], b = p[1];
  bf16x8 v;
  v[0] = (bf16)a.x; v[1] = (bf16)a.y; v[2] = (bf16)a.z; v[3] = (bf16)a.w;
  v[4] = (bf16)b.x; v[5] = (bf16)b.y; v[6] = (bf16)b.z; v[7] = (bf16)b.w;
  ((bf16x8*)out)[i] = v;
}

__global__ void init_h_kernel(const float* __restrict__ h0, bf16* __restrict__ hb) {
  int i = blockIdx.x * 256 + threadIdx.x;   // grid 256 -> 65536
  hb[i] = (bf16)h0[i];
}

// in: (R,C) f32 row-major -> out: (C,R) bf16 row-major
__global__ void transpose_cast(const float* __restrict__ in, bf16* __restrict__ out,
                               int R, int C) {
  __shared__ float t[64][65];
  int tR = blockIdx.x * 64, tC = blockIdx.y * 64;
  int tx = threadIdx.x & 63, ty = threadIdx.x >> 6;  // ty 0..3
#pragma unroll
  for (int i = 0; i < 16; ++i) {
    int r = tR + i * 4 + ty, c = tC + tx;
    t[i * 4 + ty][tx] = (r < R && c < C) ? in[(size_t)r * C + c] : 0.f;
  }
  __syncthreads();
#pragma unroll
  for (int i = 0; i < 16; ++i) {
    int c = tC + i * 4 + ty, r = tR + tx;
    if (c < C && r < R) out[(size_t)c * R + r] = (bf16)t[tx][i * 4 + ty];
  }
}

// ---------------- MFMA GEMM  (A: MxK row-major bf16, B: B^T = NxK row-major bf16) ----------
// 128x128 tile, BK=64, 256 threads (4 waves, 2x2), 16x16x32 bf16 MFMA.
// LDS XOR-swizzle (16B chunk c of row r stored at c^(r&7)) -> conflict-light reads,
// and identical layout to a future global_load_lds upgrade.
// Verified fragment mapping (guide m89/m91/m120):
//   A-frag: A[m=lane&15][k=quad*8+j]; B-frag: B^T[n=lane&15][k=quad*8+j]
//   C/D:    row m = quad*4+reg, col n = lane&15
template <int MODE>
__launch_bounds__(256, 2)
__global__ void gemm_bt(const bf16* __restrict__ A, const bf16* __restrict__ B,
                        int M, int N, int K, int lda,
                        const float* __restrict__ bias0,
                        const float* __restrict__ bias1,
                        const float* __restrict__ bias2,
                        const float* __restrict__ x0rz,
                        float* __restrict__ outA,
                        float* __restrict__ outB,
                        float* __restrict__ outC,
                        bf16* __restrict__ outBf) {
  __shared__ bf16 ldsA[128 * 64];
  __shared__ bf16 ldsB[128 * 64];
  const int tid = threadIdx.x;
  const int lane = tid & 63;
  const int wave = tid >> 6;
  const int quad = lane >> 4;
  const int l15 = lane & 15;
  const int wm = wave & 1, wn = wave >> 1;
  const int m0 = blockIdx.x * 128, n0 = blockIdx.y * 128;

  f32x4 acc[4][4] = {};

  for (int kc = 0; kc < K; kc += 64) {
#pragma unroll
    for (int i = 0; i < 4; ++i) {
      int q = i * 256 + tid;  // 16B chunk id 0..1023
      int r = q >> 3, cs = q & 7;
      int c = cs ^ (r & 7);
      int gr = m0 + r; if (gr > M - 1) gr = M - 1;  // clamp for M<128 tiles
      *(bf16x8*)(ldsA + r * 64 + cs * 8) =
          *(const bf16x8*)(A + (size_t)gr * lda + kc + c * 8);
      *(bf16x8*)(ldsB + r * 64 + cs * 8) =
          *(const bf16x8*)(B + (size_t)(n0 + r) * K + kc + c * 8);
    }
    __syncthreads();
#pragma unroll
    for (int ks = 0; ks < 2; ++ks) {
      bf16x8 af[4], bfr[4];
      int ch = ks * 4 + quad;
#pragma unroll
      for (int t = 0; t < 4; ++t) {
        int ar = wm * 64 + t * 16 + l15;
        af[t] = *(const bf16x8*)(ldsA + ar * 64 + ((ch ^ (ar & 7)) * 8));
        int br = wn * 64 + t * 16 + l15;
        bfr[t] = *(const bf16x8*)(ldsB + br * 64 + ((ch ^ (br & 7)) * 8));
      }
#pragma unroll
      for (int mt = 0; mt < 4; ++mt)
#pragma unroll
        for (int nt = 0; nt < 4; ++nt)
          acc[mt][nt] = __builtin_amdgcn_mfma_f32_16x16x32_bf16(
              af[mt], bfr[nt], acc[mt][nt], 0, 0, 0);
    }
    __syncthreads();
  }

#pragma unroll
  for (int mt = 0; mt < 4; ++mt) {
#pragma unroll
    for (int nt = 0; nt < 4; ++nt) {
#pragma unroll
      for (int i = 0; i < 4; ++i) {
        int m = m0 + wm * 64 + mt * 16 + quad * 4 + i;
        int n = n0 + wn * 64 + nt * 16 + l15;
        if (m >= M) continue;
        float v = acc[mt][nt][i];
        if (MODE == 0) {  // GEMM1: xtes = relu(.+bxe) -> f32 out + bf16 copy
          v += bias0[n];
          v = fmaxf(v, 0.f);
          outA[(size_t)m * 1024 + n] = v;
          outBf[(size_t)m * 1024 + n] = (bf16)v;
        } else if (MODE == 1) {  // GEMM2 fused: zt | xth1 | ptes
          if (n < 1024) {
            float z = v + bias0[n] + x0rz[(size_t)(m >> 6) * 2048 + 1024 + n];
            outA[(size_t)m * 1024 + n] = 1.f / (1.f + expf(-z));  // zt
          } else if (n < 2048) {
            outB[(size_t)m * 1024 + (n - 1024)] = v + bias1[n - 1024];  // xth1
          } else if (n < 2048 + C_DIM) {
            outC[(size_t)m * C_DIM + (n - 2048)] = v + bias2[n - 2048];  // ptes
          }
        } else {  // MODE 2: x0rz = x0e@[Wx0r|Wx0z] + bias
          outA[(size_t)m * 2048 + n] = v + (n < 1024 ? bias0[n] : bias1[n - 1024]);
        }
      }
    }
  }
}

// ---------------- recurrence ----------------
// 64 persistent blocks x 256 threads. Block j owns h columns [16j,16j+16).
// Whr^T / Wh1h1^T strips (16x1024 each, bf16) live in LDS for all 64 steps.
// h exchanged via double-buffered bf16 global arrays; fp32 carry in registers.
// Per-step device barrier: release fence + per-step counter + acquire fence
// (agent-scope fences handle cross-XCD L2 via buffer_wbl2/buffer_inv sc1).
__launch_bounds__(256, 1)
__global__ void recur_kernel(const bf16* __restrict__ WrecT,
                             const float* __restrict__ bhr,
                             const float* __restrict__ bh1h1,
                             const float* __restrict__ x0rz,
                             const float* __restrict__ ztAll,
                             const float* __restrict__ xth1All,
                             const float* __restrict__ h0,
                             bf16* __restrict__ hBf0,
                             bf16* __restrict__ hBf1,
                             float* __restrict__ hts,
                             unsigned* __restrict__ bar) {
  __shared__ bf16 lds[2 * 16 * 1024];  // 64 KB: [Whr^T strip | Wh1h1^T strip]
  const int tid = threadIdx.x;
  const int lane = tid & 63, wave = tid >> 6;
  const int quad = lane >> 4, l15 = lane & 15;
  const int n0 = blockIdx.x * 16;

  for (int idx = tid; idx < 2 * 16 * 128; idx += 256) {
    int mat = idx >> 11, rem = idx & 2047;
    int r = rem >> 7, c = rem & 127;                 // row in strip, 16B chunk
    int csw = (c & 0x78) | ((c ^ r) & 7);            // XOR swizzle
    *(bf16x8*)(lds + mat * 16384 + r * 1024 + csw * 8) =
        *(const bf16x8*)(WrecT + (size_t)(mat * 1024 + n0 + r) * 1024 + c * 8);
  }

  const int n = n0 + l15;
  float hb_ = bh1h1[n];
  float rb[4], hloc[4];
#pragma unroll
  for (int i = 0; i < 4; ++i) {
    int b = wave * 16 + quad * 4 + i;
    rb[i] = bhr[n] + x0rz[(size_t)b * 2048 + n];  // bhr + x0r
    hloc[i] = h0[(size_t)b * 1024 + n];           // fp32 carry
  }
  __syncthreads();

  for (int s = 0; s < 64; ++s) {
    const bf16* hR = (s & 1) ? hBf1 : hBf0;
    bf16* hW = (s & 1) ? hBf0 : hBf1;
    f32x4 racc = {0.f, 0.f, 0.f, 0.f}, hacc = {0.f, 0.f, 0.f, 0.f};
#pragma unroll 4
    for (int kb = 0; kb < 32; ++kb) {
      bf16x8 a = *(const bf16x8*)(hR + (size_t)(wave * 16 + l15) * 1024 + kb * 32 + quad * 8);
      int ch = kb * 4 + quad;
      int csw = (ch & 0x78) | ((ch ^ l15) & 7);
      bf16x8 brf = *(const bf16x8*)(lds + l15 * 1024 + csw * 8);
      bf16x8 bhf = *(const bf16x8*)(lds + 16384 + l15 * 1024 + csw * 8);
      racc = __builtin_amdgcn_mfma_f32_16x16x32_bf16(a, brf, racc, 0, 0, 0);
      hacc = __builtin_amdgcn_mfma_f32_16x16x32_bf16(a, bhf, hacc, 0, 0, 0);
    }
#pragma unroll
    for (int i = 0; i < 4; ++i) {
      int b = wave * 16 + quad * 4 + i;
      size_t mrow = (size_t)(b * 64 + s) * 1024 + n;
      float rt = 1.f / (1.f + expf(-(racc[i] + rb[i])));
      float h1v = hacc[i] + hb_;
      float th = tanhf(xth1All[mrow] + rt * h1v);
      float z = ztAll[mrow];
      float hn = (1.f - z) * th + z * hloc[i];
      hloc[i] = hn;
      hW[(size_t)b * 1024 + n] = (bf16)hn;
      hts[mrow] = hn;
    }
    if (s < 63) {
      __threadfence();      // release (drains stores, wb L2)
      __syncthreads();
      if (tid == 0) {
        atomicAdd(&bar[s * 16], 1u);
        while (__hip_atomic_load(&bar[s * 16], __ATOMIC_ACQUIRE,
                                 __HIP_MEMORY_SCOPE_AGENT) < 64u) {
          __builtin_amdgcn_s_sleep(1);
        }
      }
      __syncthreads();
      __threadfence();      // acquire (inv L1/stale L2)
    }
  }
}

// ---------------- broadcasts ----------------
__global__ void bcast_x0es(const float* __restrict__ xtes, float* __restrict__ x0es) {
  int idx = blockIdx.x * 256 + threadIdx.x;  // float4 units, 64*64*256
  int b = idx >> 14;
  int j = idx & 255;
  ((float4*)x0es)[idx] = ((const float4*)xtes)[(size_t)b * 16384 + 63 * 256 + j];
}

__global__ void bcast_p0es(const float* __restrict__ ptes, float* __restrict__ p0es) {
  int idx = blockIdx.x * 256 + threadIdx.x;
  if (idx >= B_DIM * S_DIM * C_DIM) return;
  int b = idx / (S_DIM * C_DIM);
  int rem = idx - b * (S_DIM * C_DIM);
  int c = rem % C_DIM;
  p0es[idx] = ptes[(size_t)b * (S_DIM * C_DIM) + 63 * C_DIM + c];
}

// ---------------- launch ----------------
extern "C" void kernel_launch(void* const* d_in, const int* in_sizes, int n_in,
                              void* d_out, int out_size, void* d_ws, size_t ws_size,
                              hipStream_t stream) {
  const float* x     = (const float*)d_in[0];
  const float* h0    = (const float*)d_in[1];
  const float* Wxe   = (const float*)d_in[2];
  const float* bxe   = (const float*)d_in[3];
  const float* Wep   = (const float*)d_in[4];
  const float* bep   = (const float*)d_in[5];
  const float* Whr   = (const float*)d_in[6];
  const float* bhr   = (const float*)d_in[7];
  const float* Wx0r  = (const float*)d_in[8];
  const float* bx0r  = (const float*)d_in[9];
  const float* Wxtz  = (const float*)d_in[10];
  const float* bxtz  = (const float*)d_in[11];
  const float* Wx0z  = (const float*)d_in[12];
  const float* bx0z  = (const float*)d_in[13];
  const float* Wxth1 = (const float*)d_in[14];
  const float* bxth1 = (const float*)d_in[15];
  const float* Wh1h1 = (const float*)d_in[16];
  const float* bh1h1 = (const float*)d_in[17];

  float* out   = (float*)d_out;
  float* hts   = out;                 // (64,64,1024)
  float* ptes  = out + 4194304;       // (64,64,31)
  float* p0es  = out + 4321280;       // (64,64,31)
  float* xtesO = out + 4448256;       // (64,64,1024)
  float* x0es  = out + 8642560;       // (64,64,1024)

  char* ws = (char*)d_ws;
  size_t off = 0;
  auto alloc = [&](size_t bytes) -> char* {
    char* p = ws + off;
    off += (bytes + 255) & ~(size_t)255;
    return p;
  };
  // x_bf zone is dead after GEMM1; reused for ztAll/xth1All (exact fit 32 MB)
  bf16*  xbf     = (bf16*)alloc(33554432);
  float* ztAll   = (float*)xbf;
  float* xth1All = (float*)((char*)xbf + 16777216);
  bf16*  WxeT    = (bf16*)alloc(8388608);            // 1024 x 4096
  bf16*  W2T     = (bf16*)alloc((size_t)2176 * 1024 * 2);  // [Wxtz^T;Wxth1^T;Wep^T pad]
  bf16*  WrecT   = (bf16*)alloc(4194304);            // [Whr^T;Wh1h1^T] 2048x1024
  bf16*  Wx0T    = (bf16*)alloc(4194304);            // [Wx0r^T;Wx0z^T]
  bf16*  xtesBf  = (bf16*)alloc(8388608);            // 4096 x 1024
  float* x0rz    = (float*)alloc(524288);            // 64 x 2048
  bf16*  hBf0    = (bf16*)alloc(131072);
  bf16*  hBf1    = (bf16*)alloc(131072);
  unsigned* bar  = (unsigned*)alloc(4096);           // 64 step counters, 64B apart

  hipMemsetAsync(W2T, 0, (size_t)2176 * 1024 * 2, stream);  // zero pad rows
  hipMemsetAsync(bar, 0, 4096, stream);

  cast_x_kernel<<<8192, 256, 0, stream>>>(x, xbf);
  init_h_kernel<<<256, 256, 0, stream>>>(h0, hBf0);

  dim3 tb(256);
  transpose_cast<<<dim3(64, 16), tb, 0, stream>>>(Wxe, WxeT, 4096, 1024);
  transpose_cast<<<dim3(16, 16), tb, 0, stream>>>(Whr, WrecT, 1024, 1024);
  transpose_cast<<<dim3(16, 16), tb, 0, stream>>>(Wh1h1, WrecT + 1024 * 1024, 1024, 1024);
  transpose_cast<<<dim3(16, 16), tb, 0, stream>>>(Wxtz, W2T, 1024, 1024);
  transpose_cast<<<dim3(16, 16), tb, 0, stream>>>(Wxth1, W2T + 1024 * 1024, 1024, 1024);
  transpose_cast<<<dim3(16, 1), tb, 0, stream>>>(Wep, W2T + 2048 * 1024, 1024, 31);
  transpose_cast<<<dim3(16, 16), tb, 0, stream>>>(Wx0r, Wx0T, 1024, 1024);
  transpose_cast<<<dim3(16, 16), tb, 0, stream>>>(Wx0z, Wx0T + 1024 * 1024, 1024, 1024);

  // GEMM1: xtes
  gemm_bt<0><<<dim3(32, 8), tb, 0, stream>>>(xbf, WxeT, 4096, 1024, 4096, 4096,
                                             bxe, nullptr, nullptr, nullptr,
                                             xtesO, nullptr, nullptr, xtesBf);
  // x0rz (A = xtes rows s=63, stride S*H)
  gemm_bt<2><<<dim3(1, 16), tb, 0, stream>>>(xtesBf + 63 * 1024, Wx0T, 64, 2048, 1024, 65536,
                                             bx0r, bx0z, nullptr, nullptr,
                                             x0rz, nullptr, nullptr, nullptr);
  // GEMM2 fused: zt | xth1 | ptes
  gemm_bt<1><<<dim3(32, 17), tb, 0, stream>>>(xtesBf, W2T, 4096, 2176, 1024, 1024,
                                              bxtz, bxth1, bep, x0rz,
                                              ztAll, xth1All, ptes, nullptr);

  recur_kernel<<<64, tb, 0, stream>>>(WrecT, bhr, bh1h1, x0rz, ztAll, xth1All,
                                      h0, hBf0, hBf1, hts, bar);

  bcast_x0es<<<4096, tb, 0, stream>>>(xtesO, x0es);
  bcast_p0es<<<496, tb, 0, stream>>>(ptes, p0es);
}

// Round 2
// 1081.680 us; speedup vs baseline: 1.7019x; 1.7019x over previous
//
#include <hip/hip_runtime.h>
#include <stdint.h>

// IDUCell on MI355X (gfx950).
// Algebraic facts exploited:
//   x0e  == xtes[:, S-1, :]   (x0 = x[:, -1])
//   p0e  == ptes[:, S-1, :]
//   zt   is h-independent: zt = sigmoid(xtes@Wxtz + bxtz + x0z)  -> precomputed
// R2 recurrence redesign: fence-free device sync.
//   - 4 independent batch domains (16 rows each) x 64 H-strips = 256 blocks
//   - weights strip in VGPRs (B-fragments resident), LDS only for 4-way K reduce
//   - h exchanged via relaxed AGENT-scope atomics (coherence-point, no L2 wb/inv)
//   - per-(step,domain,strip) flag stores; waiters poll 64 flags with __all()

using bf16 = __bf16;
typedef __attribute__((ext_vector_type(8))) __bf16 bf16x8;
typedef __attribute__((ext_vector_type(4))) float f32x4;

#define B_DIM 64
#define S_DIM 64
#define F_DIM 4096
#define H_DIM 1024
#define C_DIM 31

// ---------------- elementwise ----------------

__global__ void cast_x_kernel(const float* __restrict__ in, bf16* __restrict__ out) {
  int i = blockIdx.x * 256 + threadIdx.x;   // 8 elems per thread
  const float4* p = (const float4*)in + (size_t)i * 2;
  float4 a = p[0], b = p[1];
  bf16x8 v;
  v[0] = (bf16)a.x; v[1] = (bf16)a.y; v[2] = (bf16)a.z; v[3] = (bf16)a.w;
  v[4] = (bf16)b.x; v[5] = (bf16)b.y; v[6] = (bf16)b.z; v[7] = (bf16)b.w;
  ((bf16x8*)out)[i] = v;
}

// in: (R,C) f32 row-major -> out: (C,R) bf16 row-major
__global__ void transpose_cast(const float* __restrict__ in, bf16* __restrict__ out,
                               int R, int C) {
  __shared__ float t[64][65];
  int tR = blockIdx.x * 64, tC = blockIdx.y * 64;
  int tx = threadIdx.x & 63, ty = threadIdx.x >> 6;  // ty 0..3
#pragma unroll
  for (int i = 0; i < 16; ++i) {
    int r = tR + i * 4 + ty, c = tC + tx;
    t[i * 4 + ty][tx] = (r < R && c < C) ? in[(size_t)r * C + c] : 0.f;
  }
  __syncthreads();
#pragma unroll
  for (int i = 0; i < 16; ++i) {
    int c = tC + i * 4 + ty, r = tR + tx;
    if (c < C && r < R) out[(size_t)c * R + r] = (bf16)t[tx][i * 4 + ty];
  }
}

// ---------------- MFMA GEMM  (A: MxK row-major bf16, B: B^T = NxK row-major bf16) ----------
// 128x128 tile, BK=64, 256 threads (4 waves, 2x2), 16x16x32 bf16 MFMA.
template <int MODE>
__launch_bounds__(256, 2)
__global__ void gemm_bt(const bf16* __restrict__ A, const bf16* __restrict__ B,
                        int M, int N, int K, int lda,
                        const float* __restrict__ bias0,
                        const float* __restrict__ bias1,
                        const float* __restrict__ bias2,
                        const float* __restrict__ x0rz,
                        float* __restrict__ outA,
                        float* __restrict__ outB,
                        float* __restrict__ outC,
                        bf16* __restrict__ outBf) {
  __shared__ bf16 ldsA[128 * 64];
  __shared__ bf16 ldsB[128 * 64];
  const int tid = threadIdx.x;
  const int lane = tid & 63;
  const int wave = tid >> 6;
  const int quad = lane >> 4;
  const int l15 = lane & 15;
  const int wm = wave & 1, wn = wave >> 1;
  const int m0 = blockIdx.x * 128, n0 = blockIdx.y * 128;

  f32x4 acc[4][4] = {};

  for (int kc = 0; kc < K; kc += 64) {
#pragma unroll
    for (int i = 0; i < 4; ++i) {
      int q = i * 256 + tid;  // 16B chunk id 0..1023
      int r = q >> 3, cs = q & 7;
      int c = cs ^ (r & 7);
      int gr = m0 + r; if (gr > M - 1) gr = M - 1;  // clamp for M<128 tiles
      *(bf16x8*)(ldsA + r * 64 + cs * 8) =
          *(const bf16x8*)(A + (size_t)gr * lda + kc + c * 8);
      *(bf16x8*)(ldsB + r * 64 + cs * 8) =
          *(const bf16x8*)(B + (size_t)(n0 + r) * K + kc + c * 8);
    }
    __syncthreads();
#pragma unroll
    for (int ks = 0; ks < 2; ++ks) {
      bf16x8 af[4], bfr[4];
      int ch = ks * 4 + quad;
#pragma unroll
      for (int t = 0; t < 4; ++t) {
        int ar = wm * 64 + t * 16 + l15;
        af[t] = *(const bf16x8*)(ldsA + ar * 64 + ((ch ^ (ar & 7)) * 8));
        int br = wn * 64 + t * 16 + l15;
        bfr[t] = *(const bf16x8*)(ldsB + br * 64 + ((ch ^ (br & 7)) * 8));
      }
#pragma unroll
      for (int mt = 0; mt < 4; ++mt)
#pragma unroll
        for (int nt = 0; nt < 4; ++nt)
          acc[mt][nt] = __builtin_amdgcn_mfma_f32_16x16x32_bf16(
              af[mt], bfr[nt], acc[mt][nt], 0, 0, 0);
    }
    __syncthreads();
  }

#pragma unroll
  for (int mt = 0; mt < 4; ++mt) {
#pragma unroll
    for (int nt = 0; nt < 4; ++nt) {
#pragma unroll
      for (int i = 0; i < 4; ++i) {
        int m = m0 + wm * 64 + mt * 16 + quad * 4 + i;
        int n = n0 + wn * 64 + nt * 16 + l15;
        if (m >= M) continue;
        float v = acc[mt][nt][i];
        if (MODE == 0) {  // GEMM1: xtes = relu(.+bxe) -> f32 out + bf16 copy
          v += bias0[n];
          v = fmaxf(v, 0.f);
          outA[(size_t)m * 1024 + n] = v;
          outBf[(size_t)m * 1024 + n] = (bf16)v;
        } else if (MODE == 1) {  // GEMM2 fused: zt | xth1 | ptes
          if (n < 1024) {
            float z = v + bias0[n] + x0rz[(size_t)(m >> 6) * 2048 + 1024 + n];
            outA[(size_t)m * 1024 + n] = 1.f / (1.f + expf(-z));  // zt
          } else if (n < 2048) {
            outB[(size_t)m * 1024 + (n - 1024)] = v + bias1[n - 1024];  // xth1
          } else if (n < 2048 + C_DIM) {
            outC[(size_t)m * C_DIM + (n - 2048)] = v + bias2[n - 2048];  // ptes
          }
        } else {  // MODE 2: x0rz = x0e@[Wx0r|Wx0z] + bias
          outA[(size_t)m * 2048 + n] = v + (n < 1024 ? bias0[n] : bias1[n - 1024]);
        }
      }
    }
  }
}

// ---------------- recurrence (fence-free) ----------------
// 256 blocks = strip j (64, 16 H-cols each) x domain g (4, 16 batch rows each).
// 4 waves = K-quarters; weights strips resident in VGPRs; LDS 4-way reduce.
// h exchange + flags via relaxed agent-scope atomics (coherence point, no fences).
__launch_bounds__(256, 1)
__global__ void recur_kernel(const bf16* __restrict__ WrecT,
                             const float* __restrict__ bhr,
                             const float* __restrict__ bh1h1,
                             const float* __restrict__ x0rz,
                             const float* __restrict__ ztAll,
                             const float* __restrict__ xth1All,
                             const float* __restrict__ h0,
                             unsigned short* hB0,
                             unsigned short* hB1,
                             float* __restrict__ hts,
                             unsigned* __restrict__ arr) {
  __shared__ float part[4][64][8];  // 8 KB partial accumulators
  const int tid = threadIdx.x;
  const int lane = tid & 63, wave = tid >> 6;
  const int quad = lane >> 4, l15 = lane & 15;
  const int j = blockIdx.x & 63;   // H-strip
  const int g = blockIdx.x >> 6;   // batch domain
  const int n0 = j * 16;
  const int n = n0 + l15;
  const int kq = wave * 256;       // this wave's K-quarter

  // B-fragments (weight strips) into VGPRs: 2 matrices x 8 k-tiles x 16B
  bf16x8 wr[8], wh[8];
#pragma unroll
  for (int kb = 0; kb < 8; ++kb) {
    wr[kb] = *(const bf16x8*)(WrecT + (size_t)n * 1024 + kq + kb * 32 + quad * 8);
    wh[kb] = *(const bf16x8*)(WrecT + (size_t)(1024 + n) * 1024 + kq + kb * 32 + quad * 8);
  }

  // wave0 epilogue state (fp32 carry)
  float rb[4], hloc[4], hb_ = 0.f;
  if (wave == 0) {
    hb_ = bh1h1[n];
#pragma unroll
    for (int i = 0; i < 4; ++i) {
      int b = g * 16 + quad * 4 + i;
      rb[i] = bhr[n] + x0rz[(size_t)b * 2048 + n];  // bhr + x0r
      hloc[i] = h0[(size_t)b * 1024 + n];
    }
  }

  const int arow = g * 16 + l15;  // A-operand row = global batch row

  for (int s = 0; s < 64; ++s) {
    // prefetch step-s gate inputs (plain cached loads; hidden behind the poll)
    float zt[4], xh[4];
    if (wave == 0) {
#pragma unroll
      for (int i = 0; i < 4; ++i) {
        size_t mrow = ((size_t)(g * 16 + quad * 4 + i) * 64 + s) * 1024 + n;
        zt[i] = ztAll[mrow];
        xh[i] = xth1All[mrow];
      }
    }
    // wait for all 64 strips of our domain from step s-1
    if (s > 0) {
      const unsigned* a = arr + ((size_t)(s - 1) * 4 + g) * 64 + lane;
      unsigned f = __hip_atomic_load(a, __ATOMIC_RELAXED, __HIP_MEMORY_SCOPE_AGENT);
      while (!__all(f != 0)) {
        __builtin_amdgcn_s_sleep(1);
        f = __hip_atomic_load(a, __ATOMIC_RELAXED, __HIP_MEMORY_SCOPE_AGENT);
      }
      asm volatile("" ::: "memory");
    }
    // A-fragments: h rows for our domain, our K-quarter
    bf16x8 af[8];
    if (s == 0) {
#pragma unroll
      for (int kb = 0; kb < 8; ++kb) {
        const float* p = h0 + (size_t)arow * 1024 + kq + kb * 32 + quad * 8;
        float4 u0 = *(const float4*)p;
        float4 u1 = *(const float4*)(p + 4);
        bf16x8 v;
        v[0] = (bf16)u0.x; v[1] = (bf16)u0.y; v[2] = (bf16)u0.z; v[3] = (bf16)u0.w;
        v[4] = (bf16)u1.x; v[5] = (bf16)u1.y; v[6] = (bf16)u1.z; v[7] = (bf16)u1.w;
        af[kb] = v;
      }
    } else {
      const unsigned short* hR = (s & 1) ? hB0 : hB1;
#pragma unroll
      for (int kb = 0; kb < 8; ++kb) {
        const unsigned long long* p =
            (const unsigned long long*)(hR + (size_t)arow * 1024 + kq + kb * 32 + quad * 8);
        unsigned long long u0 = __hip_atomic_load(p, __ATOMIC_RELAXED, __HIP_MEMORY_SCOPE_AGENT);
        unsigned long long u1 = __hip_atomic_load(p + 1, __ATOMIC_RELAXED, __HIP_MEMORY_SCOPE_AGENT);
        union { unsigned long long q[2]; bf16x8 v; } cv;
        cv.q[0] = u0; cv.q[1] = u1;
        af[kb] = cv.v;
      }
    }
    f32x4 racc = {0.f, 0.f, 0.f, 0.f}, hacc = {0.f, 0.f, 0.f, 0.f};
#pragma unroll
    for (int kb = 0; kb < 8; ++kb) {
      racc = __builtin_amdgcn_mfma_f32_16x16x32_bf16(af[kb], wr[kb], racc, 0, 0, 0);
      hacc = __builtin_amdgcn_mfma_f32_16x16x32_bf16(af[kb], wh[kb], hacc, 0, 0, 0);
    }
    *(f32x4*)&part[wave][lane][0] = racc;
    *(f32x4*)&part[wave][lane][4] = hacc;
    __syncthreads();
    if (wave == 0) {
#pragma unroll
      for (int w = 1; w < 4; ++w) {
        racc += *(const f32x4*)&part[w][lane][0];
        hacc += *(const f32x4*)&part[w][lane][4];
      }
      unsigned short* hW = (s & 1) ? hB1 : hB0;
#pragma unroll
      for (int i = 0; i < 4; ++i) {
        int b = g * 16 + quad * 4 + i;
        size_t mrow = ((size_t)b * 64 + s) * 1024 + n;
        float rt = 1.f / (1.f + expf(-(racc[i] + rb[i])));
        float th = tanhf(xh[i] + rt * (hacc[i] + hb_));
        float hn = (1.f - zt[i]) * th + zt[i] * hloc[i];
        hloc[i] = hn;
        hts[mrow] = hn;
        union { bf16 b16; unsigned short u; } cv;
        cv.b16 = (bf16)hn;
        __hip_atomic_store(hW + (size_t)b * 1024 + n, cv.u,
                           __ATOMIC_RELAXED, __HIP_MEMORY_SCOPE_AGENT);
      }
      __builtin_amdgcn_s_waitcnt(0);  // drain h-strip stores to coherence point
      if (lane == 0)
        __hip_atomic_store(arr + ((size_t)s * 4 + g) * 64 + j, 1u,
                           __ATOMIC_RELAXED, __HIP_MEMORY_SCOPE_AGENT);
    }
    // waves 1-3 can't overwrite `part` for s+1 until their poll sees OUR flag,
    // which wave0 sets only after reading `part` -> no second barrier needed.
  }
}

// ---------------- broadcasts ----------------
__global__ void bcast_x0es(const float* __restrict__ xtes, float* __restrict__ x0es) {
  int idx = blockIdx.x * 256 + threadIdx.x;  // float4 units, 64*64*256
  int b = idx >> 14;
  int j = idx & 255;
  ((float4*)x0es)[idx] = ((const float4*)xtes)[(size_t)b * 16384 + 63 * 256 + j];
}

__global__ void bcast_p0es(const float* __restrict__ ptes, float* __restrict__ p0es) {
  int idx = blockIdx.x * 256 + threadIdx.x;
  if (idx >= B_DIM * S_DIM * C_DIM) return;
  int b = idx / (S_DIM * C_DIM);
  int rem = idx - b * (S_DIM * C_DIM);
  int c = rem % C_DIM;
  p0es[idx] = ptes[(size_t)b * (S_DIM * C_DIM) + 63 * C_DIM + c];
}

// ---------------- launch ----------------
extern "C" void kernel_launch(void* const* d_in, const int* in_sizes, int n_in,
                              void* d_out, int out_size, void* d_ws, size_t ws_size,
                              hipStream_t stream) {
  const float* x     = (const float*)d_in[0];
  const float* h0    = (const float*)d_in[1];
  const float* Wxe   = (const float*)d_in[2];
  const float* bxe   = (const float*)d_in[3];
  const float* Wep   = (const float*)d_in[4];
  const float* bep   = (const float*)d_in[5];
  const float* Whr   = (const float*)d_in[6];
  const float* bhr   = (const float*)d_in[7];
  const float* Wx0r  = (const float*)d_in[8];
  const float* bx0r  = (const float*)d_in[9];
  const float* Wxtz  = (const float*)d_in[10];
  const float* bxtz  = (const float*)d_in[11];
  const float* Wx0z  = (const float*)d_in[12];
  const float* bx0z  = (const float*)d_in[13];
  const float* Wxth1 = (const float*)d_in[14];
  const float* bxth1 = (const float*)d_in[15];
  const float* Wh1h1 = (const float*)d_in[16];
  const float* bh1h1 = (const float*)d_in[17];

  float* out   = (float*)d_out;
  float* hts   = out;                 // (64,64,1024)
  float* ptes  = out + 4194304;       // (64,64,31)
  float* p0es  = out + 4321280;       // (64,64,31)
  float* xtesO = out + 4448256;       // (64,64,1024)
  float* x0es  = out + 8642560;       // (64,64,1024)

  char* ws = (char*)d_ws;
  size_t off = 0;
  auto alloc = [&](size_t bytes) -> char* {
    char* p = ws + off;
    off += (bytes + 255) & ~(size_t)255;
    return p;
  };
  // x_bf zone is dead after GEMM1; reused for ztAll/xth1All (exact fit 32 MB)
  bf16*  xbf     = (bf16*)alloc(33554432);
  float* ztAll   = (float*)xbf;
  float* xth1All = (float*)((char*)xbf + 16777216);
  bf16*  WxeT    = (bf16*)alloc(8388608);            // 1024 x 4096
  bf16*  W2T     = (bf16*)alloc((size_t)2176 * 1024 * 2);  // [Wxtz^T;Wxth1^T;Wep^T pad]
  bf16*  WrecT   = (bf16*)alloc(4194304);            // [Whr^T;Wh1h1^T] 2048x1024
  bf16*  Wx0T    = (bf16*)alloc(4194304);            // [Wx0r^T;Wx0z^T]
  bf16*  xtesBf  = (bf16*)alloc(8388608);            // 4096 x 1024
  float* x0rz    = (float*)alloc(524288);            // 64 x 2048
  unsigned short* hB0 = (unsigned short*)alloc(131072);
  unsigned short* hB1 = (unsigned short*)alloc(131072);
  unsigned* arr  = (unsigned*)alloc(65536);          // 64 steps x 4 domains x 64 strips

  hipMemsetAsync(W2T, 0, (size_t)2176 * 1024 * 2, stream);  // zero pad rows
  hipMemsetAsync(arr, 0, 65536, stream);

  cast_x_kernel<<<8192, 256, 0, stream>>>(x, xbf);

  dim3 tb(256);
  transpose_cast<<<dim3(64, 16), tb, 0, stream>>>(Wxe, WxeT, 4096, 1024);
  transpose_cast<<<dim3(16, 16), tb, 0, stream>>>(Whr, WrecT, 1024, 1024);
  transpose_cast<<<dim3(16, 16), tb, 0, stream>>>(Wh1h1, WrecT + 1024 * 1024, 1024, 1024);
  transpose_cast<<<dim3(16, 16), tb, 0, stream>>>(Wxtz, W2T, 1024, 1024);
  transpose_cast<<<dim3(16, 16), tb, 0, stream>>>(Wxth1, W2T + 1024 * 1024, 1024, 1024);
  transpose_cast<<<dim3(16, 1), tb, 0, stream>>>(Wep, W2T + 2048 * 1024, 1024, 31);
  transpose_cast<<<dim3(16, 16), tb, 0, stream>>>(Wx0r, Wx0T, 1024, 1024);
  transpose_cast<<<dim3(16, 16), tb, 0, stream>>>(Wx0z, Wx0T + 1024 * 1024, 1024, 1024);

  // GEMM1: xtes
  gemm_bt<0><<<dim3(32, 8), tb, 0, stream>>>(xbf, WxeT, 4096, 1024, 4096, 4096,
                                             bxe, nullptr, nullptr, nullptr,
                                             xtesO, nullptr, nullptr, xtesBf);
  // x0rz (A = xtes rows s=63, stride S*H)
  gemm_bt<2><<<dim3(1, 16), tb, 0, stream>>>(xtesBf + 63 * 1024, Wx0T, 64, 2048, 1024, 65536,
                                             bx0r, bx0z, nullptr, nullptr,
                                             x0rz, nullptr, nullptr, nullptr);
  // GEMM2 fused: zt | xth1 | ptes
  gemm_bt<1><<<dim3(32, 17), tb, 0, stream>>>(xtesBf, W2T, 4096, 2176, 1024, 1024,
                                              bxtz, bxth1, bep, x0rz,
                                              ztAll, xth1All, ptes, nullptr);

  recur_kernel<<<256, tb, 0, stream>>>(WrecT, bhr, bh1h1, x0rz, ztAll, xth1All,
                                       h0, hB0, hB1, hts, arr);

  bcast_x0es<<<4096, tb, 0, stream>>>(xtesO, x0es);
  bcast_p0es<<<496, tb, 0, stream>>>(ptes, p0es);
}

// Round 3
// 970.436 us; speedup vs baseline: 1.8970x; 1.1146x over previous
//
#include <hip/hip_runtime.h>
#include <stdint.h>

// IDUCell on MI355X (gfx950).
// Algebraic facts exploited:
//   x0e  == xtes[:, S-1, :]   (x0 = x[:, -1])
//   p0e  == ptes[:, S-1, :]
//   zt   is h-independent: zt = sigmoid(xtes@Wxtz + bxtz + x0z)  -> precomputed
// R3 recurrence: tagged-data exchange, zero flags.
//   h element transmitted as u32 = (bf16 bits << 16) | step_tag. Each dword is
//   self-validating -> no producer waitcnt, no flag store, no flag-line poll
//   (R2's bottleneck: 16K atomic loads serializing on 4 flag cache lines).
//   Consumers poll the h data itself (spread over >1K lines). Double buffer +
//   exact tag check: producer can't reach step s+1 until every block of its
//   domain published step s, so buffer overwrite can't race a reader.

using bf16 = __bf16;
typedef __attribute__((ext_vector_type(8))) __bf16 bf16x8;
typedef __attribute__((ext_vector_type(4))) float f32x4;

#define B_DIM 64
#define S_DIM 64
#define F_DIM 4096
#define H_DIM 1024
#define C_DIM 31

// ---------------- elementwise ----------------

__global__ void cast_x_kernel(const float* __restrict__ in, bf16* __restrict__ out) {
  int i = blockIdx.x * 256 + threadIdx.x;   // 8 elems per thread
  const float4* p = (const float4*)in + (size_t)i * 2;
  float4 a = p[0], b = p[1];
  bf16x8 v;
  v[0] = (bf16)a.x; v[1] = (bf16)a.y; v[2] = (bf16)a.z; v[3] = (bf16)a.w;
  v[4] = (bf16)b.x; v[5] = (bf16)b.y; v[6] = (bf16)b.z; v[7] = (bf16)b.w;
  ((bf16x8*)out)[i] = v;
}

// in: (R,C) f32 row-major -> out: (C,R) bf16 row-major
__global__ void transpose_cast(const float* __restrict__ in, bf16* __restrict__ out,
                               int R, int C) {
  __shared__ float t[64][65];
  int tR = blockIdx.x * 64, tC = blockIdx.y * 64;
  int tx = threadIdx.x & 63, ty = threadIdx.x >> 6;  // ty 0..3
#pragma unroll
  for (int i = 0; i < 16; ++i) {
    int r = tR + i * 4 + ty, c = tC + tx;
    t[i * 4 + ty][tx] = (r < R && c < C) ? in[(size_t)r * C + c] : 0.f;
  }
  __syncthreads();
#pragma unroll
  for (int i = 0; i < 16; ++i) {
    int c = tC + i * 4 + ty, r = tR + tx;
    if (c < C && r < R) out[(size_t)c * R + r] = (bf16)t[tx][i * 4 + ty];
  }
}

// six 1024x1024 transposes in one launch (blockIdx.z selects matrix)
__global__ void transpose_cast_1k6(const float* __restrict__ a0, const float* __restrict__ a1,
                                   const float* __restrict__ a2, const float* __restrict__ a3,
                                   const float* __restrict__ a4, const float* __restrict__ a5,
                                   bf16* __restrict__ o0, bf16* __restrict__ o1,
                                   bf16* __restrict__ o2) {
  __shared__ float t[64][65];
  int z = blockIdx.z;
  const float* in = z == 0 ? a0 : z == 1 ? a1 : z == 2 ? a2 : z == 3 ? a3 : z == 4 ? a4 : a5;
  bf16* out = (z < 2 ? o0 : z < 4 ? o1 : o2) + (size_t)(z & 1) * 1048576;
  int tR = blockIdx.x * 64, tC = blockIdx.y * 64;
  int tx = threadIdx.x & 63, ty = threadIdx.x >> 6;
#pragma unroll
  for (int i = 0; i < 16; ++i)
    t[i * 4 + ty][tx] = in[(size_t)(tR + i * 4 + ty) * 1024 + tC + tx];
  __syncthreads();
#pragma unroll
  for (int i = 0; i < 16; ++i)
    out[(size_t)(tC + i * 4 + ty) * 1024 + tR + tx] = (bf16)t[tx][i * 4 + ty];
}

// ---------------- MFMA GEMM  (A: MxK row-major bf16, B: B^T = NxK row-major bf16) ----------
// 128x128 tile, BK=64, 256 threads (4 waves, 2x2), 16x16x32 bf16 MFMA.
template <int MODE>
__launch_bounds__(256, 2)
__global__ void gemm_bt(const bf16* __restrict__ A, const bf16* __restrict__ B,
                        int M, int N, int K, int lda,
                        const float* __restrict__ bias0,
                        const float* __restrict__ bias1,
                        const float* __restrict__ bias2,
                        const float* __restrict__ x0rz,
                        float* __restrict__ outA,
                        float* __restrict__ outB,
                        float* __restrict__ outC,
                        bf16* __restrict__ outBf) {
  __shared__ bf16 ldsA[128 * 64];
  __shared__ bf16 ldsB[128 * 64];
  const int tid = threadIdx.x;
  const int lane = tid & 63;
  const int wave = tid >> 6;
  const int quad = lane >> 4;
  const int l15 = lane & 15;
  const int wm = wave & 1, wn = wave >> 1;
  const int m0 = blockIdx.x * 128, n0 = blockIdx.y * 128;

  f32x4 acc[4][4] = {};

  for (int kc = 0; kc < K; kc += 64) {
#pragma unroll
    for (int i = 0; i < 4; ++i) {
      int q = i * 256 + tid;  // 16B chunk id 0..1023
      int r = q >> 3, cs = q & 7;
      int c = cs ^ (r & 7);
      int gr = m0 + r; if (gr > M - 1) gr = M - 1;  // clamp for M<128 tiles
      *(bf16x8*)(ldsA + r * 64 + cs * 8) =
          *(const bf16x8*)(A + (size_t)gr * lda + kc + c * 8);
      *(bf16x8*)(ldsB + r * 64 + cs * 8) =
          *(const bf16x8*)(B + (size_t)(n0 + r) * K + kc + c * 8);
    }
    __syncthreads();
#pragma unroll
    for (int ks = 0; ks < 2; ++ks) {
      bf16x8 af[4], bfr[4];
      int ch = ks * 4 + quad;
#pragma unroll
      for (int t = 0; t < 4; ++t) {
        int ar = wm * 64 + t * 16 + l15;
        af[t] = *(const bf16x8*)(ldsA + ar * 64 + ((ch ^ (ar & 7)) * 8));
        int br = wn * 64 + t * 16 + l15;
        bfr[t] = *(const bf16x8*)(ldsB + br * 64 + ((ch ^ (br & 7)) * 8));
      }
#pragma unroll
      for (int mt = 0; mt < 4; ++mt)
#pragma unroll
        for (int nt = 0; nt < 4; ++nt)
          acc[mt][nt] = __builtin_amdgcn_mfma_f32_16x16x32_bf16(
              af[mt], bfr[nt], acc[mt][nt], 0, 0, 0);
    }
    __syncthreads();
  }

#pragma unroll
  for (int mt = 0; mt < 4; ++mt) {
#pragma unroll
    for (int nt = 0; nt < 4; ++nt) {
#pragma unroll
      for (int i = 0; i < 4; ++i) {
        int m = m0 + wm * 64 + mt * 16 + quad * 4 + i;
        int n = n0 + wn * 64 + nt * 16 + l15;
        if (m >= M) continue;
        float v = acc[mt][nt][i];
        if (MODE == 0) {  // GEMM1: xtes = relu(.+bxe) -> f32 out + bf16 copy
          v += bias0[n];
          v = fmaxf(v, 0.f);
          outA[(size_t)m * 1024 + n] = v;
          outBf[(size_t)m * 1024 + n] = (bf16)v;
        } else if (MODE == 1) {  // GEMM2 fused: zt | xth1 | ptes
          if (n < 1024) {
            float z = v + bias0[n] + x0rz[(size_t)(m >> 6) * 2048 + 1024 + n];
            outA[(size_t)m * 1024 + n] = 1.f / (1.f + expf(-z));  // zt
          } else if (n < 2048) {
            outB[(size_t)m * 1024 + (n - 1024)] = v + bias1[n - 1024];  // xth1
          } else if (n < 2048 + C_DIM) {
            outC[(size_t)m * C_DIM + (n - 2048)] = v + bias2[n - 2048];  // ptes
          }
        } else {  // MODE 2: x0rz = x0e@[Wx0r|Wx0z] + bias
          outA[(size_t)m * 2048 + n] = v + (n < 1024 ? bias0[n] : bias1[n - 1024]);
        }
      }
    }
  }
}

// ---------------- recurrence (tagged-data sync) ----------------
// 256 blocks = strip j (64, 16 H-cols each) x domain g (4, 16 batch rows each).
// 4 waves = K-quarters; weight strips resident in VGPRs; LDS 4-way K reduce.
// h element: u32 = (bf16 bits << 16) | step_tag.  Poll = the data load itself.
#define TAG_OK(v, w) \
  ((((unsigned)(v) & 0xFFFFu) == (w)) & (((unsigned)((v) >> 32) & 0xFFFFu) == (w)))

__launch_bounds__(256, 1)
__global__ void recur_kernel(const bf16* __restrict__ WrecT,
                             const float* __restrict__ bhr,
                             const float* __restrict__ bh1h1,
                             const float* __restrict__ x0rz,
                             const float* __restrict__ ztAll,
                             const float* __restrict__ xth1All,
                             const float* __restrict__ h0,
                             unsigned* hT0,
                             unsigned* hT1,
                             float* __restrict__ hts) {
  __shared__ float part[4][64][8];  // 8 KB partial accumulators
  const int tid = threadIdx.x;
  const int lane = tid & 63, wave = tid >> 6;
  const int quad = lane >> 4, l15 = lane & 15;
  const int j = blockIdx.x & 63;   // H-strip
  const int g = blockIdx.x >> 6;   // batch domain
  const int n0 = j * 16;
  const int n = n0 + l15;
  const int kq = wave * 256;       // this wave's K-quarter

  // B-fragments (weight strips) into VGPRs: 2 matrices x 8 k-tiles
  bf16x8 wr[8], wh[8];
#pragma unroll
  for (int kb = 0; kb < 8; ++kb) {
    wr[kb] = *(const bf16x8*)(WrecT + (size_t)n * 1024 + kq + kb * 32 + quad * 8);
    wh[kb] = *(const bf16x8*)(WrecT + (size_t)(1024 + n) * 1024 + kq + kb * 32 + quad * 8);
  }

  // wave0 epilogue state (fp32 carry)
  float rb[4], hloc[4], hb_ = 0.f;
  if (wave == 0) {
    hb_ = bh1h1[n];
#pragma unroll
    for (int i = 0; i < 4; ++i) {
      int b = g * 16 + quad * 4 + i;
      rb[i] = bhr[n] + x0rz[(size_t)b * 2048 + n];  // bhr + x0r
      hloc[i] = h0[(size_t)b * 1024 + n];
    }
  }

  const int arow = g * 16 + l15;  // A-operand row = global batch row

  for (int s = 0; s < 64; ++s) {
    // prefetch step-s gate inputs (plain cached loads; hidden behind the poll)
    float zt[4], xh[4];
    if (wave == 0) {
#pragma unroll
      for (int i = 0; i < 4; ++i) {
        size_t mrow = ((size_t)(g * 16 + quad * 4 + i) * 64 + s) * 1024 + n;
        zt[i] = ztAll[mrow];
        xh[i] = xth1All[mrow];
      }
    }
    bf16x8 af[8];
    if (s == 0) {
#pragma unroll
      for (int kb = 0; kb < 8; ++kb) {
        const float* p = h0 + (size_t)arow * 1024 + kq + kb * 32 + quad * 8;
        float4 u0 = *(const float4*)p;
        float4 u1 = *(const float4*)(p + 4);
        bf16x8 v;
        v[0] = (bf16)u0.x; v[1] = (bf16)u0.y; v[2] = (bf16)u0.z; v[3] = (bf16)u0.w;
        v[4] = (bf16)u1.x; v[5] = (bf16)u1.y; v[6] = (bf16)u1.z; v[7] = (bf16)u1.w;
        af[kb] = v;
      }
    } else {
      const unsigned* hR = (s & 1) ? hT0 : hT1;
      const unsigned long long* base =
          (const unsigned long long*)(hR + (size_t)arow * 1024 + kq);
      const unsigned want = (unsigned)(s - 1);
      unsigned long long q[32];
      // phase 1: cheap poll on the first u64 of each chunk (8 loads/lane)
      bool ok = false;
      for (int it = 0; it < (1 << 22) && !ok; ++it) {
        bool lok = true;
#pragma unroll
        for (int kb = 0; kb < 8; ++kb) {
          unsigned long long v = __hip_atomic_load(base + kb * 16 + quad * 4,
                                                   __ATOMIC_RELAXED,
                                                   __HIP_MEMORY_SCOPE_AGENT);
          q[kb * 4] = v;
          lok &= (bool)TAG_OK(v, want);
        }
        ok = __all(lok);
      }
      // phase 2: full load of remaining 24 u64, every dword self-validated
      ok = false;
      for (int it = 0; it < (1 << 22) && !ok; ++it) {
        bool lok = true;
#pragma unroll
        for (int kb = 0; kb < 8; ++kb)
#pragma unroll
          for (int t = 1; t < 4; ++t) {
            unsigned long long v = __hip_atomic_load(base + kb * 16 + quad * 4 + t,
                                                     __ATOMIC_RELAXED,
                                                     __HIP_MEMORY_SCOPE_AGENT);
            q[kb * 4 + t] = v;
            lok &= (bool)TAG_OK(v, want);
          }
        ok = __all(lok);
      }
      // pack high halves -> bf16x8 fragments
#pragma unroll
      for (int kb = 0; kb < 8; ++kb) {
        unsigned d0 = (unsigned)q[kb * 4 + 0], d1 = (unsigned)(q[kb * 4 + 0] >> 32);
        unsigned d2 = (unsigned)q[kb * 4 + 1], d3 = (unsigned)(q[kb * 4 + 1] >> 32);
        unsigned d4 = (unsigned)q[kb * 4 + 2], d5 = (unsigned)(q[kb * 4 + 2] >> 32);
        unsigned d6 = (unsigned)q[kb * 4 + 3], d7 = (unsigned)(q[kb * 4 + 3] >> 32);
        union { unsigned p[4]; bf16x8 v; } cv;
        cv.p[0] = (d0 >> 16) | (d1 & 0xFFFF0000u);
        cv.p[1] = (d2 >> 16) | (d3 & 0xFFFF0000u);
        cv.p[2] = (d4 >> 16) | (d5 & 0xFFFF0000u);
        cv.p[3] = (d6 >> 16) | (d7 & 0xFFFF0000u);
        af[kb] = cv.v;
      }
    }
    f32x4 racc = {0.f, 0.f, 0.f, 0.f}, hacc = {0.f, 0.f, 0.f, 0.f};
#pragma unroll
    for (int kb = 0; kb < 8; ++kb) {
      racc = __builtin_amdgcn_mfma_f32_16x16x32_bf16(af[kb], wr[kb], racc, 0, 0, 0);
      hacc = __builtin_amdgcn_mfma_f32_16x16x32_bf16(af[kb], wh[kb], hacc, 0, 0, 0);
    }
    *(f32x4*)&part[wave][lane][0] = racc;
    *(f32x4*)&part[wave][lane][4] = hacc;
    __syncthreads();
    if (wave == 0) {
#pragma unroll
      for (int w = 1; w < 4; ++w) {
        racc += *(const f32x4*)&part[w][lane][0];
        hacc += *(const f32x4*)&part[w][lane][4];
      }
      unsigned* hW = (s & 1) ? hT1 : hT0;
#pragma unroll
      for (int i = 0; i < 4; ++i) {
        int b = g * 16 + quad * 4 + i;
        size_t mrow = ((size_t)b * 64 + s) * 1024 + n;
        float rt = 1.f / (1.f + expf(-(racc[i] + rb[i])));
        float th = tanhf(xh[i] + rt * (hacc[i] + hb_));
        float hn = (1.f - zt[i]) * th + zt[i] * hloc[i];
        hloc[i] = hn;
        hts[mrow] = hn;
        if (s < 63) {
          union { bf16 b16; unsigned short u; } cv;
          cv.b16 = (bf16)hn;
          __hip_atomic_store(hW + (size_t)b * 1024 + n,
                             ((unsigned)cv.u << 16) | (unsigned)s,
                             __ATOMIC_RELAXED, __HIP_MEMORY_SCOPE_AGENT);
        }
      }
      // no waitcnt, no flag: each stored dword carries its own validity tag
    }
    // waves 1-3 can't overwrite `part` for s+1 until their poll sees OUR strip's
    // tag==s, which wave0 stores only after reading `part` -> no second barrier.
  }
}

// ---------------- broadcasts ----------------
__global__ void bcast_x0es(const float* __restrict__ xtes, float* __restrict__ x0es) {
  int idx = blockIdx.x * 256 + threadIdx.x;  // float4 units, 64*64*256
  int b = idx >> 14;
  int j = idx & 255;
  ((float4*)x0es)[idx] = ((const float4*)xtes)[(size_t)b * 16384 + 63 * 256 + j];
}

__global__ void bcast_p0es(const float* __restrict__ ptes, float* __restrict__ p0es) {
  int idx = blockIdx.x * 256 + threadIdx.x;
  if (idx >= B_DIM * S_DIM * C_DIM) return;
  int b = idx / (S_DIM * C_DIM);
  int rem = idx - b * (S_DIM * C_DIM);
  int c = rem % C_DIM;
  p0es[idx] = ptes[(size_t)b * (S_DIM * C_DIM) + 63 * C_DIM + c];
}

// ---------------- launch ----------------
extern "C" void kernel_launch(void* const* d_in, const int* in_sizes, int n_in,
                              void* d_out, int out_size, void* d_ws, size_t ws_size,
                              hipStream_t stream) {
  const float* x     = (const float*)d_in[0];
  const float* h0    = (const float*)d_in[1];
  const float* Wxe   = (const float*)d_in[2];
  const float* bxe   = (const float*)d_in[3];
  const float* Wep   = (const float*)d_in[4];
  const float* bep   = (const float*)d_in[5];
  const float* Whr   = (const float*)d_in[6];
  const float* bhr   = (const float*)d_in[7];
  const float* Wx0r  = (const float*)d_in[8];
  const float* bx0r  = (const float*)d_in[9];
  const float* Wxtz  = (const float*)d_in[10];
  const float* bxtz  = (const float*)d_in[11];
  const float* Wx0z  = (const float*)d_in[12];
  const float* bx0z  = (const float*)d_in[13];
  const float* Wxth1 = (const float*)d_in[14];
  const float* bxth1 = (const float*)d_in[15];
  const float* Wh1h1 = (const float*)d_in[16];
  const float* bh1h1 = (const float*)d_in[17];

  float* out   = (float*)d_out;
  float* hts   = out;                 // (64,64,1024)
  float* ptes  = out + 4194304;       // (64,64,31)
  float* p0es  = out + 4321280;       // (64,64,31)
  float* xtesO = out + 4448256;       // (64,64,1024)
  float* x0es  = out + 8642560;       // (64,64,1024)

  char* ws = (char*)d_ws;
  size_t off = 0;
  auto alloc = [&](size_t bytes) -> char* {
    char* p = ws + off;
    off += (bytes + 255) & ~(size_t)255;
    return p;
  };
  // x_bf zone is dead after GEMM1; reused for ztAll/xth1All (exact fit 32 MB)
  bf16*  xbf     = (bf16*)alloc(33554432);
  float* ztAll   = (float*)xbf;
  float* xth1All = (float*)((char*)xbf + 16777216);
  bf16*  WxeT    = (bf16*)alloc(8388608);            // 1024 x 4096
  bf16*  W2T     = (bf16*)alloc((size_t)2176 * 1024 * 2);  // [Wxtz^T;Wxth1^T;Wep^T pad]
  bf16*  WrecT   = (bf16*)alloc(4194304);            // [Whr^T;Wh1h1^T] 2048x1024
  bf16*  Wx0T    = (bf16*)alloc(4194304);            // [Wx0r^T;Wx0z^T]
  bf16*  xtesBf  = (bf16*)alloc(8388608);            // 4096 x 1024
  float* x0rz    = (float*)alloc(524288);            // 64 x 2048
  unsigned* hT0  = (unsigned*)alloc(262144);         // tagged h, step-even
  unsigned* hT1  = (unsigned*)alloc(262144);         // tagged h, step-odd

  hipMemsetAsync(W2T, 0, (size_t)2176 * 1024 * 2, stream);  // zero pad rows

  cast_x_kernel<<<8192, 256, 0, stream>>>(x, xbf);

  dim3 tb(256);
  transpose_cast<<<dim3(64, 16), tb, 0, stream>>>(Wxe, WxeT, 4096, 1024);
  transpose_cast_1k6<<<dim3(16, 16, 6), tb, 0, stream>>>(
      Whr, Wh1h1, Wxtz, Wxth1, Wx0r, Wx0z, WrecT, W2T, Wx0T);
  transpose_cast<<<dim3(16, 1), tb, 0, stream>>>(Wep, W2T + 2048 * 1024, 1024, 31);

  // GEMM1: xtes
  gemm_bt<0><<<dim3(32, 8), tb, 0, stream>>>(xbf, WxeT, 4096, 1024, 4096, 4096,
                                             bxe, nullptr, nullptr, nullptr,
                                             xtesO, nullptr, nullptr, xtesBf);
  // x0rz (A = xtes rows s=63, stride S*H)
  gemm_bt<2><<<dim3(1, 16), tb, 0, stream>>>(xtesBf + 63 * 1024, Wx0T, 64, 2048, 1024, 65536,
                                             bx0r, bx0z, nullptr, nullptr,
                                             x0rz, nullptr, nullptr, nullptr);
  // GEMM2 fused: zt | xth1 | ptes
  gemm_bt<1><<<dim3(32, 17), tb, 0, stream>>>(xtesBf, W2T, 4096, 2176, 1024, 1024,
                                              bxtz, bxth1, bep, x0rz,
                                              ztAll, xth1All, ptes, nullptr);

  recur_kernel<<<256, tb, 0, stream>>>(WrecT, bhr, bh1h1, x0rz, ztAll, xth1All,
                                       h0, hT0, hT1, hts);

  bcast_x0es<<<4096, tb, 0, stream>>>(xtesO, x0es);
  bcast_p0es<<<496, tb, 0, stream>>>(ptes, p0es);
}

// Round 4
// 666.071 us; speedup vs baseline: 2.7639x; 1.4570x over previous
//
#include <hip/hip_runtime.h>
#include <stdint.h>

// IDUCell on MI355X (gfx950).
// Algebraic facts exploited:
//   x0e  == xtes[:, S-1, :]   (x0 = x[:, -1])
//   p0e  == ptes[:, S-1, :]
//   zt   is h-independent: zt = sigmoid(xtes@Wxtz + bxtz + x0z)  -> precomputed
// R4:
//   - recurrence: 128 blocks (32 strips x 4 domains). Tagged h exchange kept
//     (u32 = bf16<<16 | step tag, self-validating, no fences/flags) but loads
//     are now block-cooperative and lane-contiguous (R3's killer: scattered 8B
//     coherent requests). Sample-poll (32 threads, 1 vec per producer stripe)
//     gates one full coalesced 64 KB read -> LDS (swizzled) -> ds_read frags.
//   - GEMMs: __builtin_amdgcn_global_load_lds width=16 staging (m97 pattern).

using bf16 = __bf16;
typedef __attribute__((ext_vector_type(8))) __bf16 bf16x8;
typedef __attribute__((ext_vector_type(4))) float f32x4;

#define B_DIM 64
#define S_DIM 64
#define F_DIM 4096
#define H_DIM 1024
#define C_DIM 31

// ---------------- elementwise ----------------

__global__ void cast_x_kernel(const float* __restrict__ in, bf16* __restrict__ out) {
  int i = blockIdx.x * 256 + threadIdx.x;   // 8 elems per thread
  const float4* p = (const float4*)in + (size_t)i * 2;
  float4 a = p[0], b = p[1];
  bf16x8 v;
  v[0] = (bf16)a.x; v[1] = (bf16)a.y; v[2] = (bf16)a.z; v[3] = (bf16)a.w;
  v[4] = (bf16)b.x; v[5] = (bf16)b.y; v[6] = (bf16)b.z; v[7] = (bf16)b.w;
  ((bf16x8*)out)[i] = v;
}

// h0 -> tagged buffer0: u32 = (bf16 bits << 16) | tag 0
__global__ void tag_h0_kernel(const float* __restrict__ h0, unsigned* __restrict__ hT0) {
  int i = blockIdx.x * 256 + threadIdx.x;   // grid 256 -> 65536
  union { bf16 b; unsigned short u; } cv;
  cv.b = (bf16)h0[i];
  __hip_atomic_store(hT0 + i, ((unsigned)cv.u << 16), __ATOMIC_RELAXED,
                     __HIP_MEMORY_SCOPE_AGENT);
}

// in: (R,C) f32 row-major -> out: (C,R) bf16 row-major
__global__ void transpose_cast(const float* __restrict__ in, bf16* __restrict__ out,
                               int R, int C) {
  __shared__ float t[64][65];
  int tR = blockIdx.x * 64, tC = blockIdx.y * 64;
  int tx = threadIdx.x & 63, ty = threadIdx.x >> 6;  // ty 0..3
#pragma unroll
  for (int i = 0; i < 16; ++i) {
    int r = tR + i * 4 + ty, c = tC + tx;
    t[i * 4 + ty][tx] = (r < R && c < C) ? in[(size_t)r * C + c] : 0.f;
  }
  __syncthreads();
#pragma unroll
  for (int i = 0; i < 16; ++i) {
    int c = tC + i * 4 + ty, r = tR + tx;
    if (c < C && r < R) out[(size_t)c * R + r] = (bf16)t[tx][i * 4 + ty];
  }
}

// six 1024x1024 transposes in one launch (blockIdx.z selects matrix)
__global__ void transpose_cast_1k6(const float* __restrict__ a0, const float* __restrict__ a1,
                                   const float* __restrict__ a2, const float* __restrict__ a3,
                                   const float* __restrict__ a4, const float* __restrict__ a5,
                                   bf16* __restrict__ o0, bf16* __restrict__ o1,
                                   bf16* __restrict__ o2) {
  __shared__ float t[64][65];
  int z = blockIdx.z;
  const float* in = z == 0 ? a0 : z == 1 ? a1 : z == 2 ? a2 : z == 3 ? a3 : z == 4 ? a4 : a5;
  bf16* out = (z < 2 ? o0 : z < 4 ? o1 : o2) + (size_t)(z & 1) * 1048576;
  int tR = blockIdx.x * 64, tC = blockIdx.y * 64;
  int tx = threadIdx.x & 63, ty = threadIdx.x >> 6;
#pragma unroll
  for (int i = 0; i < 16; ++i)
    t[i * 4 + ty][tx] = in[(size_t)(tR + i * 4 + ty) * 1024 + tC + tx];
  __syncthreads();
#pragma unroll
  for (int i = 0; i < 16; ++i)
    out[(size_t)(tC + i * 4 + ty) * 1024 + tR + tx] = (bf16)t[tx][i * 4 + ty];
}

// ---------------- MFMA GEMM  (A: MxK row-major bf16, B: B^T = NxK row-major bf16) ----------
// 128x128 tile, BK=64, 256 threads (4 waves, 2x2), 16x16x32 bf16 MFMA.
// Staging via global_load_lds width=16: XOR swizzle applied to the SOURCE
// address so the lane-linear LDS write produces the same swizzled layout.
template <int MODE>
__launch_bounds__(256, 2)
__global__ void gemm_bt(const bf16* __restrict__ A, const bf16* __restrict__ B,
                        int M, int N, int K, int lda,
                        const float* __restrict__ bias0,
                        const float* __restrict__ bias1,
                        const float* __restrict__ bias2,
                        const float* __restrict__ x0rz,
                        float* __restrict__ outA,
                        float* __restrict__ outB,
                        float* __restrict__ outC,
                        bf16* __restrict__ outBf) {
  __shared__ bf16 ldsA[128 * 64];
  __shared__ bf16 ldsB[128 * 64];
  const int tid = threadIdx.x;
  const int lane = tid & 63;
  const int wave = tid >> 6;
  const int quad = lane >> 4;
  const int l15 = lane & 15;
  const int wm = wave & 1, wn = wave >> 1;
  const int m0 = blockIdx.x * 128, n0 = blockIdx.y * 128;

  f32x4 acc[4][4] = {};

  for (int kc = 0; kc < K; kc += 64) {
#pragma unroll
    for (int i = 0; i < 4; ++i) {
      int qb = i * 256 + wave * 64;   // wave's 16B-chunk base (uniform)
      int q = qb + lane;
      int r = q >> 3, cs = q & 7;
      int c = cs ^ (r & 7);           // swizzle on the source side
      int gr = m0 + r; if (gr > M - 1) gr = M - 1;  // clamp for M<128 tiles
      __builtin_amdgcn_global_load_lds(
          (const __attribute__((address_space(1))) unsigned int*)(A + (size_t)gr * lda + kc + c * 8),
          (__attribute__((address_space(3))) unsigned int*)(ldsA + (size_t)qb * 8),
          16, 0, 0);
      __builtin_amdgcn_global_load_lds(
          (const __attribute__((address_space(1))) unsigned int*)(B + (size_t)(n0 + r) * K + kc + c * 8),
          (__attribute__((address_space(3))) unsigned int*)(ldsB + (size_t)qb * 8),
          16, 0, 0);
    }
    __syncthreads();
#pragma unroll
    for (int ks = 0; ks < 2; ++ks) {
      bf16x8 af[4], bfr[4];
      int ch = ks * 4 + quad;
#pragma unroll
      for (int t = 0; t < 4; ++t) {
        int ar = wm * 64 + t * 16 + l15;
        af[t] = *(const bf16x8*)(ldsA + ar * 64 + ((ch ^ (ar & 7)) * 8));
        int br = wn * 64 + t * 16 + l15;
        bfr[t] = *(const bf16x8*)(ldsB + br * 64 + ((ch ^ (br & 7)) * 8));
      }
#pragma unroll
      for (int mt = 0; mt < 4; ++mt)
#pragma unroll
        for (int nt = 0; nt < 4; ++nt)
          acc[mt][nt] = __builtin_amdgcn_mfma_f32_16x16x32_bf16(
              af[mt], bfr[nt], acc[mt][nt], 0, 0, 0);
    }
    __syncthreads();
  }

#pragma unroll
  for (int mt = 0; mt < 4; ++mt) {
#pragma unroll
    for (int nt = 0; nt < 4; ++nt) {
#pragma unroll
      for (int i = 0; i < 4; ++i) {
        int m = m0 + wm * 64 + mt * 16 + quad * 4 + i;
        int n = n0 + wn * 64 + nt * 16 + l15;
        if (m >= M) continue;
        float v = acc[mt][nt][i];
        if (MODE == 0) {  // GEMM1: xtes = relu(.+bxe) -> f32 out + bf16 copy
          v += bias0[n];
          v = fmaxf(v, 0.f);
          outA[(size_t)m * 1024 + n] = v;
          outBf[(size_t)m * 1024 + n] = (bf16)v;
        } else if (MODE == 1) {  // GEMM2 fused: zt | xth1 | ptes
          if (n < 1024) {
            float z = v + bias0[n] + x0rz[(size_t)(m >> 6) * 2048 + 1024 + n];
            outA[(size_t)m * 1024 + n] = 1.f / (1.f + expf(-z));  // zt
          } else if (n < 2048) {
            outB[(size_t)m * 1024 + (n - 1024)] = v + bias1[n - 1024];  // xth1
          } else if (n < 2048 + C_DIM) {
            outC[(size_t)m * C_DIM + (n - 2048)] = v + bias2[n - 2048];  // ptes
          }
        } else {  // MODE 2: x0rz = x0e@[Wx0r|Wx0z] + bias
          outA[(size_t)m * 2048 + n] = v + (n < 1024 ? bias0[n] : bias1[n - 1024]);
        }
      }
    }
  }
}

// ---------------- recurrence (tagged, cooperative coalesced) ----------------
// 128 blocks: j = blockIdx>>2 (strip of 32 H-cols), g = blockIdx&3 (16 rows).
// Weights (both strips) resident in VGPRs; 4 waves split K; LDS 4-way reduce.
#define TAG_OK(v, w) \
  ((((unsigned)(v) & 0xFFFFu) == (w)) & (((unsigned)((v) >> 32) & 0xFFFFu) == (w)))

__launch_bounds__(256, 1)
__global__ void recur_kernel(const bf16* __restrict__ WrecT,
                             const float* __restrict__ bhr,
                             const float* __restrict__ bh1h1,
                             const float* __restrict__ x0rz,
                             const float* __restrict__ ztAll,
                             const float* __restrict__ xth1All,
                             const float* __restrict__ h0,
                             unsigned* hT0,
                             unsigned* hT1,
                             float* __restrict__ hts) {
  __shared__ bf16 ldsA[16 * 1024];   // 32 KB staged h (16B-chunk XOR swizzle)
  __shared__ float part[4][64][16];  // 16 KB partials
  const int tid = threadIdx.x;
  const int lane = tid & 63, wave = tid >> 6;
  const int quad = lane >> 4, l15 = lane & 15;
  const int j = blockIdx.x >> 2;   // H-strip (cols 32j..32j+32)
  const int g = blockIdx.x & 3;    // batch domain (rows 16g..16g+16)
  const int kq = wave * 256;       // this wave's K-quarter

  // resident weight B-fragments: [ntile][ktile], both matrices (128 VGPRs)
  bf16x8 wr[2][8], wh[2][8];
#pragma unroll
  for (int tn = 0; tn < 2; ++tn) {
    int row = j * 32 + tn * 16 + l15;
#pragma unroll
    for (int kb = 0; kb < 8; ++kb) {
      wr[tn][kb] = *(const bf16x8*)(WrecT + (size_t)row * 1024 + kq + kb * 32 + quad * 8);
      wh[tn][kb] = *(const bf16x8*)(WrecT + (size_t)(1024 + row) * 1024 + kq + kb * 32 + quad * 8);
    }
  }

  // wave0 epilogue state (fp32 carry)
  float rb[2][4], hloc[2][4], hb2[2];
  if (wave == 0) {
#pragma unroll
    for (int tn = 0; tn < 2; ++tn) {
      int col = j * 32 + tn * 16 + l15;
      hb2[tn] = bh1h1[col];
#pragma unroll
      for (int i = 0; i < 4; ++i) {
        int b = g * 16 + quad * 4 + i;
        rb[tn][i] = bhr[col] + x0rz[(size_t)b * 2048 + col];
        hloc[tn][i] = h0[(size_t)b * 1024 + col];
      }
    }
  }

  for (int s = 0; s < 64; ++s) {
    const unsigned want = (unsigned)s;
    const unsigned* src = ((s & 1) ? hT1 : hT0) + (size_t)g * 16 * 1024;
    // wave0 prefetch of step-s gate inputs (normal cached loads)
    float zt[2][4], xh[2][4];
    if (wave == 0) {
#pragma unroll
      for (int tn = 0; tn < 2; ++tn)
#pragma unroll
        for (int i = 0; i < 4; ++i) {
          size_t mrow = ((size_t)(g * 16 + quad * 4 + i) * 64 + s) * 1024 + j * 32 + tn * 16 + l15;
          zt[tn][i] = ztAll[mrow];
          xh[tn][i] = xth1All[mrow];
        }
    }
    // ---- sample poll: thread t<32 checks one 16B vec of producer stripe t ----
    // (doubles as the block-wide barrier separating step s-1 use of ldsA)
    {
      int pend = (tid < 32) ? 1 : 0;
      const unsigned long long* sp =
          (const unsigned long long*)(src + (size_t)(tid & 15) * 1024 + (tid & 31) * 32);
      int iters = 0;
      while (true) {
        if (pend) {
          unsigned long long a = __hip_atomic_load(sp, __ATOMIC_RELAXED, __HIP_MEMORY_SCOPE_AGENT);
          unsigned long long b = __hip_atomic_load(sp + 1, __ATOMIC_RELAXED, __HIP_MEMORY_SCOPE_AGENT);
          if (TAG_OK(a, want) && TAG_OK(b, want)) pend = 0;
        }
        if (__syncthreads_count(pend) == 0) break;
        if (++iters > (1 << 16)) break;  // fail-safe: no hang
        __builtin_amdgcn_s_sleep(1);
      }
    }
    // ---- full cooperative load: thread t <-> vec t (16B) of rows 0..15 ----
    const unsigned long long* s64 = (const unsigned long long*)src;  // row*512 + t*2
#pragma unroll
    for (int half = 0; half < 2; ++half) {
      unsigned long long q0[8], q1[8];
#pragma unroll
      for (int r8 = 0; r8 < 8; ++r8) {
        const unsigned long long* p = s64 + (size_t)(half * 8 + r8) * 512 + tid * 2;
        q0[r8] = __hip_atomic_load(p, __ATOMIC_RELAXED, __HIP_MEMORY_SCOPE_AGENT);
        q1[r8] = __hip_atomic_load(p + 1, __ATOMIC_RELAXED, __HIP_MEMORY_SCOPE_AGENT);
      }
      unsigned miss = 0;
#pragma unroll
      for (int r8 = 0; r8 < 8; ++r8)
        if (!(TAG_OK(q0[r8], want) && TAG_OK(q1[r8], want))) miss |= 1u << r8;
      for (int it = 0; miss && it < (1 << 14); ++it) {
#pragma unroll
        for (int r8 = 0; r8 < 8; ++r8)
          if (miss & (1u << r8)) {
            const unsigned long long* p = s64 + (size_t)(half * 8 + r8) * 512 + tid * 2;
            unsigned long long a = __hip_atomic_load(p, __ATOMIC_RELAXED, __HIP_MEMORY_SCOPE_AGENT);
            unsigned long long b = __hip_atomic_load(p + 1, __ATOMIC_RELAXED, __HIP_MEMORY_SCOPE_AGENT);
            if (TAG_OK(a, want) && TAG_OK(b, want)) {
              q0[r8] = a; q1[r8] = b;
              miss &= ~(1u << r8);
            }
          }
      }
      // pack high halves -> bf16, ds_write_b64 into swizzled chunk layout
#pragma unroll
      for (int r8 = 0; r8 < 8; ++r8) {
        int r = half * 8 + r8;
        unsigned d0 = (unsigned)q0[r8], d1 = (unsigned)(q0[r8] >> 32);
        unsigned d2 = (unsigned)q1[r8], d3 = (unsigned)(q1[r8] >> 32);
        unsigned long long pk =
            ((unsigned long long)((d2 >> 16) | (d3 & 0xFFFF0000u)) << 32) |
            ((d0 >> 16) | (d1 & 0xFFFF0000u));
        char* lp = (char*)ldsA + r * 2048 + (((tid >> 1) ^ (r & 7)) * 16) + (tid & 1) * 8;
        *(unsigned long long*)lp = pk;
      }
    }
    __syncthreads();
    // ---- MFMA: A-frags from LDS, weights from VGPR ----
    f32x4 racc[2] = {}, hacc[2] = {};
#pragma unroll
    for (int kb = 0; kb < 8; ++kb) {
      int ch = wave * 32 + kb * 4 + quad;
      bf16x8 af = *(const bf16x8*)((char*)ldsA + l15 * 2048 + ((ch ^ (l15 & 7)) * 16));
      racc[0] = __builtin_amdgcn_mfma_f32_16x16x32_bf16(af, wr[0][kb], racc[0], 0, 0, 0);
      racc[1] = __builtin_amdgcn_mfma_f32_16x16x32_bf16(af, wr[1][kb], racc[1], 0, 0, 0);
      hacc[0] = __builtin_amdgcn_mfma_f32_16x16x32_bf16(af, wh[0][kb], hacc[0], 0, 0, 0);
      hacc[1] = __builtin_amdgcn_mfma_f32_16x16x32_bf16(af, wh[1][kb], hacc[1], 0, 0, 0);
    }
    *(f32x4*)&part[wave][lane][0]  = racc[0];
    *(f32x4*)&part[wave][lane][4]  = racc[1];
    *(f32x4*)&part[wave][lane][8]  = hacc[0];
    *(f32x4*)&part[wave][lane][12] = hacc[1];
    __syncthreads();
    if (wave == 0) {
#pragma unroll
      for (int w = 1; w < 4; ++w) {
        racc[0] += *(const f32x4*)&part[w][lane][0];
        racc[1] += *(const f32x4*)&part[w][lane][4];
        hacc[0] += *(const f32x4*)&part[w][lane][8];
        hacc[1] += *(const f32x4*)&part[w][lane][12];
      }
      unsigned* dst = (s & 1) ? hT0 : hT1;  // buffer (s+1)&1
#pragma unroll
      for (int tn = 0; tn < 2; ++tn)
#pragma unroll
        for (int i = 0; i < 4; ++i) {
          int b = g * 16 + quad * 4 + i;
          int col = j * 32 + tn * 16 + l15;
          size_t mrow = ((size_t)b * 64 + s) * 1024 + col;
          float rt = 1.f / (1.f + expf(-(racc[tn][i] + rb[tn][i])));
          float th = tanhf(xh[tn][i] + rt * (hacc[tn][i] + hb2[tn]));
          float hn = (1.f - zt[tn][i]) * th + zt[tn][i] * hloc[tn][i];
          hloc[tn][i] = hn;
          hts[mrow] = hn;
          if (s < 63) {
            union { bf16 b16; unsigned short u; } cv;
            cv.b16 = (bf16)hn;
            __hip_atomic_store(dst + (size_t)b * 1024 + col,
                               ((unsigned)cv.u << 16) | (unsigned)(s + 1),
                               __ATOMIC_RELAXED, __HIP_MEMORY_SCOPE_AGENT);
          }
        }
    }
    // next step's sample-poll barrier protects ldsA reuse.
  }
}

// ---------------- broadcasts ----------------
__global__ void bcast_x0es(const float* __restrict__ xtes, float* __restrict__ x0es) {
  int idx = blockIdx.x * 256 + threadIdx.x;  // float4 units, 64*64*256
  int b = idx >> 14;
  int j = idx & 255;
  ((float4*)x0es)[idx] = ((const float4*)xtes)[(size_t)b * 16384 + 63 * 256 + j];
}

__global__ void bcast_p0es(const float* __restrict__ ptes, float* __restrict__ p0es) {
  int idx = blockIdx.x * 256 + threadIdx.x;
  if (idx >= B_DIM * S_DIM * C_DIM) return;
  int b = idx / (S_DIM * C_DIM);
  int rem = idx - b * (S_DIM * C_DIM);
  int c = rem % C_DIM;
  p0es[idx] = ptes[(size_t)b * (S_DIM * C_DIM) + 63 * C_DIM + c];
}

// ---------------- launch ----------------
extern "C" void kernel_launch(void* const* d_in, const int* in_sizes, int n_in,
                              void* d_out, int out_size, void* d_ws, size_t ws_size,
                              hipStream_t stream) {
  const float* x     = (const float*)d_in[0];
  const float* h0    = (const float*)d_in[1];
  const float* Wxe   = (const float*)d_in[2];
  const float* bxe   = (const float*)d_in[3];
  const float* Wep   = (const float*)d_in[4];
  const float* bep   = (const float*)d_in[5];
  const float* Whr   = (const float*)d_in[6];
  const float* bhr   = (const float*)d_in[7];
  const float* Wx0r  = (const float*)d_in[8];
  const float* bx0r  = (const float*)d_in[9];
  const float* Wxtz  = (const float*)d_in[10];
  const float* bxtz  = (const float*)d_in[11];
  const float* Wx0z  = (const float*)d_in[12];
  const float* bx0z  = (const float*)d_in[13];
  const float* Wxth1 = (const float*)d_in[14];
  const float* bxth1 = (const float*)d_in[15];
  const float* Wh1h1 = (const float*)d_in[16];
  const float* bh1h1 = (const float*)d_in[17];

  float* out   = (float*)d_out;
  float* hts   = out;                 // (64,64,1024)
  float* ptes  = out + 4194304;       // (64,64,31)
  float* p0es  = out + 4321280;       // (64,64,31)
  float* xtesO = out + 4448256;       // (64,64,1024)
  float* x0es  = out + 8642560;       // (64,64,1024)

  char* ws = (char*)d_ws;
  size_t off = 0;
  auto alloc = [&](size_t bytes) -> char* {
    char* p = ws + off;
    off += (bytes + 255) & ~(size_t)255;
    return p;
  };
  // x_bf zone is dead after GEMM1; reused for ztAll/xth1All (exact fit 32 MB)
  bf16*  xbf     = (bf16*)alloc(33554432);
  float* ztAll   = (float*)xbf;
  float* xth1All = (float*)((char*)xbf + 16777216);
  bf16*  WxeT    = (bf16*)alloc(8388608);            // 1024 x 4096
  bf16*  W2T     = (bf16*)alloc((size_t)2176 * 1024 * 2);  // [Wxtz^T;Wxth1^T;Wep^T pad]
  bf16*  WrecT   = (bf16*)alloc(4194304);            // [Whr^T;Wh1h1^T] 2048x1024
  bf16*  Wx0T    = (bf16*)alloc(4194304);            // [Wx0r^T;Wx0z^T]
  bf16*  xtesBf  = (bf16*)alloc(8388608);            // 4096 x 1024
  float* x0rz    = (float*)alloc(524288);            // 64 x 2048
  unsigned* hT0  = (unsigned*)alloc(262144);         // tagged h, even steps
  unsigned* hT1  = (unsigned*)alloc(262144);         // tagged h, odd steps

  hipMemsetAsync(W2T, 0, (size_t)2176 * 1024 * 2, stream);  // zero pad rows

  cast_x_kernel<<<8192, 256, 0, stream>>>(x, xbf);
  tag_h0_kernel<<<256, 256, 0, stream>>>(h0, hT0);

  dim3 tb(256);
  transpose_cast<<<dim3(64, 16), tb, 0, stream>>>(Wxe, WxeT, 4096, 1024);
  transpose_cast_1k6<<<dim3(16, 16, 6), tb, 0, stream>>>(
      Whr, Wh1h1, Wxtz, Wxth1, Wx0r, Wx0z, WrecT, W2T, Wx0T);
  transpose_cast<<<dim3(16, 1), tb, 0, stream>>>(Wep, W2T + 2048 * 1024, 1024, 31);

  // GEMM1: xtes
  gemm_bt<0><<<dim3(32, 8), tb, 0, stream>>>(xbf, WxeT, 4096, 1024, 4096, 4096,
                                             bxe, nullptr, nullptr, nullptr,
                                             xtesO, nullptr, nullptr, xtesBf);
  // x0rz (A = xtes rows s=63, stride S*H)
  gemm_bt<2><<<dim3(1, 16), tb, 0, stream>>>(xtesBf + 63 * 1024, Wx0T, 64, 2048, 1024, 65536,
                                             bx0r, bx0z, nullptr, nullptr,
                                             x0rz, nullptr, nullptr, nullptr);
  // GEMM2 fused: zt | xth1 | ptes
  gemm_bt<1><<<dim3(32, 17), tb, 0, stream>>>(xtesBf, W2T, 4096, 2176, 1024, 1024,
                                              bxtz, bxth1, bep, x0rz,
                                              ztAll, xth1All, ptes, nullptr);

  recur_kernel<<<128, tb, 0, stream>>>(WrecT, bhr, bh1h1, x0rz, ztAll, xth1All,
                                       h0, hT0, hT1, hts);

  bcast_x0es<<<4096, tb, 0, stream>>>(xtesO, x0es);
  bcast_p0es<<<496, tb, 0, stream>>>(ptes, p0es);
}

// Round 5
// 605.836 us; speedup vs baseline: 3.0387x; 1.0994x over previous
//
#include <hip/hip_runtime.h>
#include <stdint.h>

// IDUCell on MI355X (gfx950).
// Algebraic facts exploited:
//   x0e  == xtes[:, S-1, :]   (x0 = x[:, -1])
//   p0e  == ptes[:, S-1, :]
//   zt   is h-independent: zt = sigmoid(xtes@Wxtz + bxtz + x0z)  -> precomputed
// R5:
//   - recurrence: 64 blocks = 16 strips(64 cols) x 4 domains(16 batch rows).
//     Each wave owns 16 cols with FULL K resident in VGPRs (no LDS reduce, no
//     2nd barrier, epilogue parallel across waves). No sample poll: straight
//     coalesced cooperative tagged load with per-vec retry. LDS double buffer
//     -> exactly one __syncthreads per step.
//   - 6 kernels + 2 memsets total: cast+tag merged, all transposes in one
//     flat kernel, x0es/p0es broadcasts fused into GEMM epilogues, x0rz via
//     K-split-4 atomics.

using bf16 = __bf16;
typedef __attribute__((ext_vector_type(8))) __bf16 bf16x8;
typedef __attribute__((ext_vector_type(4))) float f32x4;

#define B_DIM 64
#define S_DIM 64
#define F_DIM 4096
#define H_DIM 1024
#define C_DIM 31

// ---------------- cast x -> bf16  +  tag h0 ----------------
__global__ void cast_tag_kernel(const float* __restrict__ x, bf16* __restrict__ xbf,
                                const float* __restrict__ h0, unsigned* __restrict__ hT0) {
  int bx = blockIdx.x;
  if (bx < 8192) {
    int i = bx * 256 + threadIdx.x;   // 8 elems per thread
    const float4* p = (const float4*)x + (size_t)i * 2;
    float4 a = p[0], b = p[1];
    bf16x8 v;
    v[0] = (bf16)a.x; v[1] = (bf16)a.y; v[2] = (bf16)a.z; v[3] = (bf16)a.w;
    v[4] = (bf16)b.x; v[5] = (bf16)b.y; v[6] = (bf16)b.z; v[7] = (bf16)b.w;
    ((bf16x8*)xbf)[i] = v;
  } else {
    int i = (bx - 8192) * 256 + threadIdx.x;  // 65536 total
    union { bf16 b; unsigned short u; } cv;
    cv.b = (bf16)h0[i];
    __hip_atomic_store(hT0 + i, ((unsigned)cv.u << 16), __ATOMIC_RELAXED,
                       __HIP_MEMORY_SCOPE_AGENT);
  }
}

// ---------------- all weight transposes, one launch ----------------
__device__ __forceinline__ void tr64(const float* __restrict__ in, bf16* __restrict__ out,
                                     int R, int C, int tR, int tC) {
  __shared__ float t[64][65];
  int tx = threadIdx.x & 63, ty = threadIdx.x >> 6;  // ty 0..3
#pragma unroll
  for (int i = 0; i < 16; ++i) {
    int r = tR + i * 4 + ty, c = tC + tx;
    t[i * 4 + ty][tx] = (r < R && c < C) ? in[(size_t)r * C + c] : 0.f;
  }
  __syncthreads();
#pragma unroll
  for (int i = 0; i < 16; ++i) {
    int c = tC + i * 4 + ty, r = tR + tx;
    if (c < C && r < R) out[(size_t)c * R + r] = (bf16)t[tx][i * 4 + ty];
  }
}

// flat grid 2576: [0,1024) Wxe (64x16 tiles); [1024,2560) six 1024^2; [2560,2576) Wep
__global__ void transpose_all(const float* __restrict__ Wxe, bf16* __restrict__ WxeT,
                              const float* __restrict__ a0, const float* __restrict__ a1,
                              const float* __restrict__ a2, const float* __restrict__ a3,
                              const float* __restrict__ a4, const float* __restrict__ a5,
                              bf16* __restrict__ o0, bf16* __restrict__ o1,
                              bf16* __restrict__ o2,
                              const float* __restrict__ Wep, bf16* __restrict__ WepT) {
  int id = blockIdx.x;
  if (id < 1024) {
    tr64(Wxe, WxeT, 4096, 1024, (id & 63) * 64, (id >> 6) * 64);
  } else if (id < 2560) {
    int q = id - 1024, z = q >> 8, t = q & 255;
    const float* in = z == 0 ? a0 : z == 1 ? a1 : z == 2 ? a2 : z == 3 ? a3 : z == 4 ? a4 : a5;
    bf16* out = (z < 2 ? o0 : z < 4 ? o1 : o2) + (size_t)(z & 1) * 1048576;
    tr64(in, out, 1024, 1024, (t & 15) * 64, (t >> 4) * 64);
  } else {
    tr64(Wep, WepT, 1024, 31, (id - 2560) * 64, 0);
  }
}

// ---------------- MFMA GEMM  (A: MxK row-major bf16, B: B^T = NxK row-major bf16) ----------
// 128x128 tile, BK=64, 256 threads (4 waves, 2x2), 16x16x32 bf16 MFMA.
// global_load_lds width=16; XOR swizzle applied on the SOURCE address.
// MODE 2 uses gridDim.z K-split with atomicAdd epilogue (outA pre-zeroed).
template <int MODE>
__launch_bounds__(256, 2)
__global__ void gemm_bt(const bf16* __restrict__ A, const bf16* __restrict__ B,
                        int M, int N, int K, int lda,
                        const float* __restrict__ bias0,
                        const float* __restrict__ bias1,
                        const float* __restrict__ bias2,
                        const float* __restrict__ x0rz,
                        float* __restrict__ outA,
                        float* __restrict__ outB,
                        float* __restrict__ outC,
                        float* __restrict__ outD,
                        bf16* __restrict__ outBf) {
  __shared__ bf16 ldsA[128 * 64];
  __shared__ bf16 ldsB[128 * 64];
  const int tid = threadIdx.x;
  const int lane = tid & 63;
  const int wave = tid >> 6;
  const int quad = lane >> 4;
  const int l15 = lane & 15;
  const int wm = wave & 1, wn = wave >> 1;
  const int m0 = blockIdx.x * 128, n0 = blockIdx.y * 128;
  const int kPer = K / gridDim.z;
  const int k0 = blockIdx.z * kPer;

  f32x4 acc[4][4] = {};

  for (int kc = k0; kc < k0 + kPer; kc += 64) {
#pragma unroll
    for (int i = 0; i < 4; ++i) {
      int qb = i * 256 + wave * 64;   // wave's 16B-chunk base (uniform)
      int q = qb + lane;
      int r = q >> 3, cs = q & 7;
      int c = cs ^ (r & 7);           // swizzle on the source side
      int gr = m0 + r; if (gr > M - 1) gr = M - 1;  // clamp for M<128 tiles
      __builtin_amdgcn_global_load_lds(
          (const __attribute__((address_space(1))) unsigned int*)(A + (size_t)gr * lda + kc + c * 8),
          (__attribute__((address_space(3))) unsigned int*)(ldsA + (size_t)qb * 8),
          16, 0, 0);
      __builtin_amdgcn_global_load_lds(
          (const __attribute__((address_space(1))) unsigned int*)(B + (size_t)(n0 + r) * K + kc + c * 8),
          (__attribute__((address_space(3))) unsigned int*)(ldsB + (size_t)qb * 8),
          16, 0, 0);
    }
    __syncthreads();
#pragma unroll
    for (int ks = 0; ks < 2; ++ks) {
      bf16x8 af[4], bfr[4];
      int ch = ks * 4 + quad;
#pragma unroll
      for (int t = 0; t < 4; ++t) {
        int ar = wm * 64 + t * 16 + l15;
        af[t] = *(const bf16x8*)(ldsA + ar * 64 + ((ch ^ (ar & 7)) * 8));
        int br = wn * 64 + t * 16 + l15;
        bfr[t] = *(const bf16x8*)(ldsB + br * 64 + ((ch ^ (br & 7)) * 8));
      }
#pragma unroll
      for (int mt = 0; mt < 4; ++mt)
#pragma unroll
        for (int nt = 0; nt < 4; ++nt)
          acc[mt][nt] = __builtin_amdgcn_mfma_f32_16x16x32_bf16(
              af[mt], bfr[nt], acc[mt][nt], 0, 0, 0);
    }
    __syncthreads();
  }

#pragma unroll
  for (int mt = 0; mt < 4; ++mt) {
#pragma unroll
    for (int nt = 0; nt < 4; ++nt) {
#pragma unroll
      for (int i = 0; i < 4; ++i) {
        int m = m0 + wm * 64 + mt * 16 + quad * 4 + i;
        int n = n0 + wn * 64 + nt * 16 + l15;
        if (m >= M) continue;
        float v = acc[mt][nt][i];
        if (MODE == 0) {  // GEMM1: xtes = relu(.+bxe) -> f32 + bf16; fuse x0es
          v += bias0[n];
          v = fmaxf(v, 0.f);
          outA[(size_t)m * 1024 + n] = v;
          outBf[(size_t)m * 1024 + n] = (bf16)v;
          if ((m & 63) == 63) {  // row s=63 -> broadcast to x0es[b, :, n]
            size_t base = (size_t)(m >> 6) * 64 * 1024 + n;
            for (int sp = 0; sp < 64; ++sp) outD[base + (size_t)sp * 1024] = v;
          }
        } else if (MODE == 1) {  // GEMM2 fused: zt | xth1 | ptes (+p0es)
          if (n < 1024) {
            float z = v + bias0[n] + x0rz[(size_t)(m >> 6) * 2048 + 1024 + n];
            outA[(size_t)m * 1024 + n] = 1.f / (1.f + expf(-z));  // zt
          } else if (n < 2048) {
            outB[(size_t)m * 1024 + (n - 1024)] = v + bias1[n - 1024];  // xth1
          } else if (n < 2048 + C_DIM) {
            float pv = v + bias2[n - 2048];
            outC[(size_t)m * C_DIM + (n - 2048)] = pv;  // ptes
            if ((m & 63) == 63) {  // -> p0es[b, :, c]
              size_t base = (size_t)(m >> 6) * 64 * C_DIM + (n - 2048);
              for (int sp = 0; sp < 64; ++sp) outD[base + (size_t)sp * C_DIM] = pv;
            }
          }
        } else {  // MODE 2: x0rz partial (K-split), atomic accumulate
          if (k0 == 0) v += (n < 1024 ? bias0[n] : bias1[n - 1024]);
          atomicAdd(outA + (size_t)m * 2048 + n, v);
        }
      }
    }
  }
}

// ---------------- recurrence (tagged, full-K per wave) ----------------
// 64 blocks: j = bx>>2 (strip of 64 cols), g = bx&3 (16 batch rows).
// Wave w owns cols [64j+16w, +16) with full-K weights in VGPRs (256 regs).
// Per step: coalesced cooperative tagged load (retry per vec) -> LDS dbuf ->
// one __syncthreads -> 64 MFMA -> per-wave epilogue + tagged publish.
// Safety induction: publishing tag s+1 requires the whole block completed its
// cooperative read of tag s (barrier + full-K MFMA data dependence), so buffer
// (s+1)&1 is only overwritten after every same-domain block has finished
// reading tag s-1 from it. One barrier per step is sufficient; tag retries
// provide all cross-block ordering. No fences anywhere.
#define TAG_OK(v, w) \
  ((((unsigned)(v) & 0xFFFFu) == (w)) & (((unsigned)((v) >> 32) & 0xFFFFu) == (w)))

__launch_bounds__(256, 1)
__global__ void recur_kernel(const bf16* __restrict__ WrecT,
                             const float* __restrict__ bhr,
                             const float* __restrict__ bh1h1,
                             const float* __restrict__ x0rz,
                             const float* __restrict__ ztAll,
                             const float* __restrict__ xth1All,
                             const float* __restrict__ h0,
                             unsigned* hT0,
                             unsigned* hT1,
                             float* __restrict__ hts) {
  __shared__ bf16 ldsA[2][16 * 1024];  // 2 x 32 KB staged h, 16B-chunk XOR swizzle
  const int tid = threadIdx.x;
  const int lane = tid & 63, wave = tid >> 6;
  const int quad = lane >> 4, l15 = lane & 15;
  const int j = blockIdx.x >> 2;   // strip (cols 64j..64j+64)
  const int g = blockIdx.x & 3;    // batch domain (rows 16g..16g+16)
  const int col = j * 64 + wave * 16 + l15;

  // full-K resident weights for this lane's column (2 matrices x 32 k-tiles)
  bf16x8 wr[32], wh[32];
#pragma unroll
  for (int kb = 0; kb < 32; ++kb) {
    wr[kb] = *(const bf16x8*)(WrecT + (size_t)col * 1024 + kb * 32 + quad * 8);
    wh[kb] = *(const bf16x8*)(WrecT + (size_t)(1024 + col) * 1024 + kb * 32 + quad * 8);
  }
  float hb_ = bh1h1[col];
  float rb[4], hloc[4];
#pragma unroll
  for (int i = 0; i < 4; ++i) {
    int b = g * 16 + quad * 4 + i;
    rb[i] = bhr[col] + x0rz[(size_t)b * 2048 + col];  // bhr + x0r
    hloc[i] = h0[(size_t)b * 1024 + col];             // fp32 carry
  }

  for (int s = 0; s < 64; ++s) {
    const unsigned want = (unsigned)s;
    const unsigned long long* src =
        (const unsigned long long*)(((s & 1) ? hT1 : hT0) + (size_t)g * 16384);
    // prefetch step-s gate inputs (independent; issued before the retry spin)
    float zt[4], xh[4];
#pragma unroll
    for (int i = 0; i < 4; ++i) {
      size_t mrow = ((size_t)(g * 16 + quad * 4 + i) * 64 + s) * 1024 + col;
      zt[i] = ztAll[mrow];
      xh[i] = xth1All[mrow];
    }
    // cooperative tagged load: thread t <-> 16B vec t of each of 16 rows
    bf16* dstL = ldsA[s & 1];
#pragma unroll
    for (int half = 0; half < 2; ++half) {
      unsigned long long q0[8], q1[8];
#pragma unroll
      for (int r8 = 0; r8 < 8; ++r8) {
        const unsigned long long* p = src + (size_t)(half * 8 + r8) * 512 + tid * 2;
        q0[r8] = __hip_atomic_load(p, __ATOMIC_RELAXED, __HIP_MEMORY_SCOPE_AGENT);
        q1[r8] = __hip_atomic_load(p + 1, __ATOMIC_RELAXED, __HIP_MEMORY_SCOPE_AGENT);
      }
      unsigned miss = 0;
#pragma unroll
      for (int r8 = 0; r8 < 8; ++r8)
        if (!(TAG_OK(q0[r8], want) && TAG_OK(q1[r8], want))) miss |= 1u << r8;
      for (int it = 0; miss && it < (1 << 20); ++it) {
#pragma unroll
        for (int r8 = 0; r8 < 8; ++r8)
          if (miss & (1u << r8)) {
            const unsigned long long* p = src + (size_t)(half * 8 + r8) * 512 + tid * 2;
            unsigned long long a = __hip_atomic_load(p, __ATOMIC_RELAXED, __HIP_MEMORY_SCOPE_AGENT);
            unsigned long long b = __hip_atomic_load(p + 1, __ATOMIC_RELAXED, __HIP_MEMORY_SCOPE_AGENT);
            if (TAG_OK(a, want) && TAG_OK(b, want)) {
              q0[r8] = a; q1[r8] = b;
              miss &= ~(1u << r8);
            }
          }
      }
      // pack high halves -> bf16, write into swizzled chunk layout
#pragma unroll
      for (int r8 = 0; r8 < 8; ++r8) {
        int r = half * 8 + r8;
        unsigned d0 = (unsigned)q0[r8], d1 = (unsigned)(q0[r8] >> 32);
        unsigned d2 = (unsigned)q1[r8], d3 = (unsigned)(q1[r8] >> 32);
        unsigned long long pk =
            ((unsigned long long)((d2 >> 16) | (d3 & 0xFFFF0000u)) << 32) |
            ((d0 >> 16) | (d1 & 0xFFFF0000u));
        int cc = ((tid >> 1) & 0x78) | (((tid >> 1) ^ r) & 7);
        *(unsigned long long*)((char*)dstL + r * 2048 + cc * 16 + (tid & 1) * 8) = pk;
      }
    }
    __syncthreads();  // the single per-step barrier
    // full-K MFMA: A from LDS, weights from VGPR
    f32x4 racc = {0.f, 0.f, 0.f, 0.f}, hacc = {0.f, 0.f, 0.f, 0.f};
#pragma unroll
    for (int kb = 0; kb < 32; ++kb) {
      int ch = kb * 4 + quad;
      bf16x8 af = *(const bf16x8*)((char*)dstL + l15 * 2048 +
                                   (((ch & 0x78) | ((ch ^ l15) & 7)) * 16));
      racc = __builtin_amdgcn_mfma_f32_16x16x32_bf16(af, wr[kb], racc, 0, 0, 0);
      hacc = __builtin_amdgcn_mfma_f32_16x16x32_bf16(af, wh[kb], hacc, 0, 0, 0);
    }
    // per-wave epilogue + publish
    unsigned* dst = (s & 1) ? hT0 : hT1;
#pragma unroll
    for (int i = 0; i < 4; ++i) {
      int b = g * 16 + quad * 4 + i;
      size_t mrow = ((size_t)b * 64 + s) * 1024 + col;
      float rt = 1.f / (1.f + expf(-(racc[i] + rb[i])));
      float th = tanhf(xh[i] + rt * (hacc[i] + hb_));
      float hn = (1.f - zt[i]) * th + zt[i] * hloc[i];
      hloc[i] = hn;
      hts[mrow] = hn;
      if (s < 63) {
        union { bf16 b16; unsigned short u; } cv;
        cv.b16 = (bf16)hn;
        __hip_atomic_store(dst + (size_t)b * 1024 + col,
                           ((unsigned)cv.u << 16) | (unsigned)(s + 1),
                           __ATOMIC_RELAXED, __HIP_MEMORY_SCOPE_AGENT);
      }
    }
    // no trailing barrier: next step writes the other LDS buffer, and tag
    // dependencies prevent any wave from running >1 step ahead of its block.
  }
}

// ---------------- launch ----------------
extern "C" void kernel_launch(void* const* d_in, const int* in_sizes, int n_in,
                              void* d_out, int out_size, void* d_ws, size_t ws_size,
                              hipStream_t stream) {
  const float* x     = (const float*)d_in[0];
  const float* h0    = (const float*)d_in[1];
  const float* Wxe   = (const float*)d_in[2];
  const float* bxe   = (const float*)d_in[3];
  const float* Wep   = (const float*)d_in[4];
  const float* bep   = (const float*)d_in[5];
  const float* Whr   = (const float*)d_in[6];
  const float* bhr   = (const float*)d_in[7];
  const float* Wx0r  = (const float*)d_in[8];
  const float* bx0r  = (const float*)d_in[9];
  const float* Wxtz  = (const float*)d_in[10];
  const float* bxtz  = (const float*)d_in[11];
  const float* Wx0z  = (const float*)d_in[12];
  const float* bx0z  = (const float*)d_in[13];
  const float* Wxth1 = (const float*)d_in[14];
  const float* bxth1 = (const float*)d_in[15];
  const float* Wh1h1 = (const float*)d_in[16];
  const float* bh1h1 = (const float*)d_in[17];

  float* out   = (float*)d_out;
  float* hts   = out;                 // (64,64,1024)
  float* ptes  = out + 4194304;       // (64,64,31)
  float* p0es  = out + 4321280;       // (64,64,31)
  float* xtesO = out + 4448256;       // (64,64,1024)
  float* x0es  = out + 8642560;       // (64,64,1024)

  char* ws = (char*)d_ws;
  size_t off = 0;
  auto alloc = [&](size_t bytes) -> char* {
    char* p = ws + off;
    off += (bytes + 255) & ~(size_t)255;
    return p;
  };
  // x_bf zone is dead after GEMM1; reused for ztAll/xth1All (exact fit 32 MB)
  bf16*  xbf     = (bf16*)alloc(33554432);
  float* ztAll   = (float*)xbf;
  float* xth1All = (float*)((char*)xbf + 16777216);
  bf16*  WxeT    = (bf16*)alloc(8388608);            // 1024 x 4096
  bf16*  W2T     = (bf16*)alloc((size_t)2176 * 1024 * 2);  // [Wxtz^T;Wxth1^T;Wep^T pad]
  bf16*  WrecT   = (bf16*)alloc(4194304);            // [Whr^T;Wh1h1^T] 2048x1024
  bf16*  Wx0T    = (bf16*)alloc(4194304);            // [Wx0r^T;Wx0z^T]
  bf16*  xtesBf  = (bf16*)alloc(8388608);            // 4096 x 1024
  float* x0rz    = (float*)alloc(524288);            // 64 x 2048
  unsigned* hT0  = (unsigned*)alloc(262144);         // tagged h, even steps
  unsigned* hT1  = (unsigned*)alloc(262144);         // tagged h, odd steps

  hipMemsetAsync(W2T, 0, (size_t)2176 * 1024 * 2, stream);  // zero pad rows
  hipMemsetAsync(x0rz, 0, 524288, stream);                  // atomic K-split acc

  dim3 tb(256);
  cast_tag_kernel<<<8448, tb, 0, stream>>>(x, xbf, h0, hT0);
  transpose_all<<<2576, tb, 0, stream>>>(Wxe, WxeT,
                                         Whr, Wh1h1, Wxtz, Wxth1, Wx0r, Wx0z,
                                         WrecT, W2T, Wx0T,
                                         Wep, W2T + 2048 * 1024);

  // GEMM1: xtes (+ fused x0es broadcast)
  gemm_bt<0><<<dim3(32, 8), tb, 0, stream>>>(xbf, WxeT, 4096, 1024, 4096, 4096,
                                             bxe, nullptr, nullptr, nullptr,
                                             xtesO, nullptr, nullptr, x0es, xtesBf);
  // x0rz = x0e@[Wx0r|Wx0z]+b, K-split 4 with atomic accumulate
  gemm_bt<2><<<dim3(1, 16, 4), tb, 0, stream>>>(xtesBf + 63 * 1024, Wx0T, 64, 2048, 1024, 65536,
                                                bx0r, bx0z, nullptr, nullptr,
                                                x0rz, nullptr, nullptr, nullptr, nullptr);
  // GEMM2 fused: zt | xth1 | ptes (+ fused p0es broadcast)
  gemm_bt<1><<<dim3(32, 17), tb, 0, stream>>>(xtesBf, W2T, 4096, 2176, 1024, 1024,
                                              bxtz, bxth1, bep, x0rz,
                                              ztAll, xth1All, ptes, p0es, nullptr);

  recur_kernel<<<64, tb, 0, stream>>>(WrecT, bhr, bh1h1, x0rz, ztAll, xth1All,
                                      h0, hT0, hT1, hts);
}